// Round 5
// baseline (207.419 us; speedup 1.0000x reference)
//
#include <hip/hip_runtime.h>
#include <hip/hip_bf16.h>

#define B_ 2
#define S_ 1024
#define D_ 768
#define H_ 12
#define HD_ 64
#define FF_ 3072
#define E_ 32768
#define QS_ 2304   // fused QKV row stride
#define NSPLIT 4   // attention KV splits
#define BHS (B_ * H_ * S_)   // 24576 partial rows per split

typedef short bf16x8 __attribute__((ext_vector_type(8)));
typedef float f32x4 __attribute__((ext_vector_type(4)));

// XOR swizzle: 8-elem seg s of row r lives at elem offset SW(r,s)
#define SW(row, seg) ((((seg) ^ ((row) & 7)) * 8))

__device__ __forceinline__ unsigned short f2bf(float f) {
    __hip_bfloat16 h = __float2bfloat16(f);
    return __builtin_bit_cast(unsigned short, h);
}
__device__ __forceinline__ float bf2f(unsigned short u) {
    unsigned int v = ((unsigned int)u) << 16;
    return __builtin_bit_cast(float, v);
}
__device__ __forceinline__ float gelu_exact(float x) {
    return 0.5f * x * (1.0f + erff(x * 0.70710678118654752f));
}

// ---------------- fast -1 fill for winner (replaces 40us runtime fillBuffer) ----------------
__global__ __launch_bounds__(256) void fill_winner_kernel(int* __restrict__ winner)
{
    const int idx = (blockIdx.x * 256 + threadIdx.x) * 4;   // grid 1024 covers S_*S_
    int4 v; v.x = -1; v.y = -1; v.z = -1; v.w = -1;
    *reinterpret_cast<int4*>(&winner[idx]) = v;
}

// ---------------- LayerNorm: f32 in -> bf16 out (row = 768) ----------------
__global__ __launch_bounds__(256) void ln_kernel(
    const float* __restrict__ x, const float* __restrict__ g,
    const float* __restrict__ b, unsigned short* __restrict__ out)
{
    const int row = blockIdx.x;
    const int t = threadIdx.x;
    const float* xr = x + (size_t)row * D_;
    float v0 = xr[t], v1 = xr[t + 256], v2 = xr[t + 512];
    float s = v0 + v1 + v2, s2 = v0 * v0 + v1 * v1 + v2 * v2;
    for (int m = 32; m; m >>= 1) { s += __shfl_xor(s, m); s2 += __shfl_xor(s2, m); }
    __shared__ float red[8];
    const int w = t >> 6;
    if ((t & 63) == 0) { red[w] = s; red[4 + w] = s2; }
    __syncthreads();
    s = red[0] + red[1] + red[2] + red[3];
    s2 = red[4] + red[5] + red[6] + red[7];
    const float mean = s * (1.f / D_);
    const float var = s2 * (1.f / D_) - mean * mean;
    const float rstd = rsqrtf(var + 1e-5f);
    unsigned short* orow = out + (size_t)row * D_;
    orow[t]       = f2bf((v0 - mean) * rstd * g[t]       + b[t]);
    orow[t + 256] = f2bf((v1 - mean) * rstd * g[t + 256] + b[t + 256]);
    orow[t + 512] = f2bf((v2 - mean) * rstd * g[t + 512] + b[t + 512]);
}

// ------------- all weight transposes + bias concat in ONE launch -------------
__global__ __launch_bounds__(256) void wtrans_all_kernel(
    const float* __restrict__ Wq, const float* __restrict__ Wk, const float* __restrict__ Wv,
    const float* __restrict__ Wo, const float* __restrict__ W1, const float* __restrict__ W2,
    unsigned short* __restrict__ wqkvt, unsigned short* __restrict__ wot,
    unsigned short* __restrict__ w1t, unsigned short* __restrict__ w2t,
    const float* __restrict__ bq, const float* __restrict__ bk, const float* __restrict__ bv,
    float* __restrict__ bqkv)
{
    const int z = blockIdx.z;
    const float* src; unsigned short* dst; int K, N, nb, kb;
    if (z < 4) {
        if (blockIdx.x >= 24 || blockIdx.y >= 24) return;
        K = 768; N = 768; nb = blockIdx.x * 32; kb = blockIdx.y * 32;
        src = (z == 0) ? Wq : (z == 1) ? Wk : (z == 2) ? Wv : Wo;
        dst = (z == 3) ? wot : wqkvt + (size_t)z * 768 * 768;
    } else if (z == 4) {
        if (blockIdx.y >= 24) return;
        K = 768; N = 3072; nb = blockIdx.x * 32; kb = blockIdx.y * 32;
        src = W1; dst = w1t;
    } else {
        if (blockIdx.y >= 24) return;
        K = 3072; N = 768; nb = blockIdx.y * 32; kb = blockIdx.x * 32;
        src = W2; dst = w2t;
    }
    __shared__ float tile[32][33];
    const int tx = threadIdx.x & 31, ty = threadIdx.x >> 5;
    for (int r = 0; r < 32; r += 8)
        tile[ty + r][tx] = src[(size_t)(kb + ty + r) * N + nb + tx];
    __syncthreads();
    for (int r = 0; r < 32; r += 8)
        dst[(size_t)(nb + ty + r) * K + kb + tx] = f2bf(tile[tx][ty + r]);
    if (z == 0 && blockIdx.x == 0 && blockIdx.y == 0) {
        for (int i = threadIdx.x; i < QS_; i += 256)
            bqkv[i] = (i < 768) ? bq[i] : (i < 1536) ? bk[i - 768] : bv[i - 1536];
    }
}

// ---------------- 64x64 GEMM (Wo): C = (A @ Bt^T + bias) [+res] ----------------
template<bool RES, bool OUTBF>
__global__ __launch_bounds__(256) void gemm_kernel(
    const unsigned short* __restrict__ A, const unsigned short* __restrict__ Bt,
    const float* __restrict__ bias, const float* __restrict__ res,
    void* __restrict__ outp, int M, int N, int K)
{
    __shared__ unsigned short As[64][40];
    __shared__ unsigned short Bs[64][40];
    const int m0 = blockIdx.y * 64, n0 = blockIdx.x * 64;
    const int t = threadIdx.x;
    const int w = t >> 6, l = t & 63;
    const int wm = w >> 1, wn = w & 1;
    const int r = l & 15, g = l >> 4;
    const int srow = t >> 2, sseg = t & 3;
    f32x4 acc[2][2] = {};
    for (int k0 = 0; k0 < K; k0 += 32) {
        __syncthreads();
        const uint4 av = *reinterpret_cast<const uint4*>(A + (size_t)(m0 + srow) * K + k0 + sseg * 8);
        *reinterpret_cast<uint4*>(&As[srow][sseg * 8]) = av;
        const uint4 bv = *reinterpret_cast<const uint4*>(Bt + (size_t)(n0 + srow) * K + k0 + sseg * 8);
        *reinterpret_cast<uint4*>(&Bs[srow][sseg * 8]) = bv;
        __syncthreads();
        bf16x8 af[2], bfr[2];
        af[0]  = *reinterpret_cast<const bf16x8*>(&As[wm * 32 + r][g * 8]);
        af[1]  = *reinterpret_cast<const bf16x8*>(&As[wm * 32 + 16 + r][g * 8]);
        bfr[0] = *reinterpret_cast<const bf16x8*>(&Bs[wn * 32 + r][g * 8]);
        bfr[1] = *reinterpret_cast<const bf16x8*>(&Bs[wn * 32 + 16 + r][g * 8]);
        for (int m = 0; m < 2; m++)
            for (int n = 0; n < 2; n++)
                acc[m][n] = __builtin_amdgcn_mfma_f32_16x16x32_bf16(af[m], bfr[n], acc[m][n], 0, 0, 0);
    }
    for (int m = 0; m < 2; m++)
        for (int n = 0; n < 2; n++) {
            const int col = n0 + wn * 32 + n * 16 + r;
            const float bvv = bias[col];
            for (int j = 0; j < 4; j++) {
                const int row = m0 + wm * 32 + m * 16 + g * 4 + j;
                float v = acc[m][n][j] + bvv;
                if (RES) v += res[(size_t)row * N + col];
                if (OUTBF) ((unsigned short*)outp)[(size_t)row * N + col] = f2bf(v);
                else       ((float*)outp)[(size_t)row * N + col] = v;
            }
        }
}

// ---------------- 64x64 split-K GEMM (W2): partial[z][M][N] f32, no bias ----------------
__global__ __launch_bounds__(256) void gemm_splitk_kernel(
    const unsigned short* __restrict__ A, const unsigned short* __restrict__ Bt,
    float* __restrict__ part, int M, int N, int K, int klen)
{
    __shared__ unsigned short As[64][40];
    __shared__ unsigned short Bs[64][40];
    const int m0 = blockIdx.y * 64, n0 = blockIdx.x * 64;
    const int kbeg = blockIdx.z * klen;
    const int t = threadIdx.x;
    const int w = t >> 6, l = t & 63;
    const int wm = w >> 1, wn = w & 1;
    const int r = l & 15, g = l >> 4;
    const int srow = t >> 2, sseg = t & 3;
    f32x4 acc[2][2] = {};
    for (int k0 = kbeg; k0 < kbeg + klen; k0 += 32) {
        __syncthreads();
        const uint4 av = *reinterpret_cast<const uint4*>(A + (size_t)(m0 + srow) * K + k0 + sseg * 8);
        *reinterpret_cast<uint4*>(&As[srow][sseg * 8]) = av;
        const uint4 bv = *reinterpret_cast<const uint4*>(Bt + (size_t)(n0 + srow) * K + k0 + sseg * 8);
        *reinterpret_cast<uint4*>(&Bs[srow][sseg * 8]) = bv;
        __syncthreads();
        bf16x8 af[2], bfr[2];
        af[0]  = *reinterpret_cast<const bf16x8*>(&As[wm * 32 + r][g * 8]);
        af[1]  = *reinterpret_cast<const bf16x8*>(&As[wm * 32 + 16 + r][g * 8]);
        bfr[0] = *reinterpret_cast<const bf16x8*>(&Bs[wn * 32 + r][g * 8]);
        bfr[1] = *reinterpret_cast<const bf16x8*>(&Bs[wn * 32 + 16 + r][g * 8]);
        for (int m = 0; m < 2; m++)
            for (int n = 0; n < 2; n++)
                acc[m][n] = __builtin_amdgcn_mfma_f32_16x16x32_bf16(af[m], bfr[n], acc[m][n], 0, 0, 0);
    }
    float* op = part + (size_t)blockIdx.z * M * N;
    for (int m = 0; m < 2; m++)
        for (int n = 0; n < 2; n++) {
            const int col = n0 + wn * 32 + n * 16 + r;
            for (int j = 0; j < 4; j++) {
                const int row = m0 + wm * 32 + m * 16 + g * 4 + j;
                op[(size_t)row * N + col] = acc[m][n][j];
            }
        }
}

// ---------------- W2 reduce: d_out = x2 + b2 + p0 + p1 ----------------
__global__ __launch_bounds__(256) void w2_reduce_kernel(
    const float* __restrict__ part, const float* __restrict__ x2,
    const float* __restrict__ b2, float* __restrict__ out)
{
    const int idx = (blockIdx.x * 256 + threadIdx.x) * 4;
    const int col = idx % D_;
    const float4 p0 = *reinterpret_cast<const float4*>(&part[idx]);
    const float4 p1 = *reinterpret_cast<const float4*>(&part[(size_t)B_ * S_ * D_ + idx]);
    const float4 xr = *reinterpret_cast<const float4*>(&x2[idx]);
    const float4 bb = *reinterpret_cast<const float4*>(&b2[col]);
    float4 o;
    o.x = xr.x + bb.x + p0.x + p1.x;
    o.y = xr.y + bb.y + p0.y + p1.y;
    o.z = xr.z + bb.z + p0.z + p1.z;
    o.w = xr.w + bb.w + p0.w + p1.w;
    *reinterpret_cast<float4*>(&out[idx]) = o;
}

// ---------------- 128x128 GEMM, BK=64, swizzled LDS (QKV fused, W1) ----------------
template<bool GELU, bool OUTBF>
__global__ __launch_bounds__(256) void gemm128_kernel(
    const unsigned short* __restrict__ A, const unsigned short* __restrict__ Bt,
    const float* __restrict__ bias, void* __restrict__ outp,
    int M, int N, int K, int scale_below)
{
    __shared__ unsigned short As[128][64];
    __shared__ unsigned short Bs[128][64];
    const int m0 = blockIdx.y * 128, n0 = blockIdx.x * 128;
    const int t = threadIdx.x;
    const int w = t >> 6, l = t & 63;
    const int wm = w >> 1, wn = w & 1;
    const int lr = l & 15, g = l >> 4;
    f32x4 acc[4][4] = {};
    for (int k0 = 0; k0 < K; k0 += 64) {
        __syncthreads();
        for (int i = 0; i < 4; i++) {
            const int idx = i * 256 + t;
            const int row = idx >> 3, seg = idx & 7;
            *reinterpret_cast<uint4*>(&As[row][SW(row, seg)]) =
                *reinterpret_cast<const uint4*>(A + (size_t)(m0 + row) * K + k0 + seg * 8);
            *reinterpret_cast<uint4*>(&Bs[row][SW(row, seg)]) =
                *reinterpret_cast<const uint4*>(Bt + (size_t)(n0 + row) * K + k0 + seg * 8);
        }
        __syncthreads();
        for (int kk = 0; kk < 2; kk++) {
            bf16x8 af[4], bfr[4];
            for (int m = 0; m < 4; m++) {
                const int r = wm * 64 + m * 16 + lr;
                af[m] = *reinterpret_cast<const bf16x8*>(&As[r][SW(r, kk * 4 + g)]);
            }
            for (int n = 0; n < 4; n++) {
                const int r = wn * 64 + n * 16 + lr;
                bfr[n] = *reinterpret_cast<const bf16x8*>(&Bs[r][SW(r, kk * 4 + g)]);
            }
            for (int m = 0; m < 4; m++)
                for (int n = 0; n < 4; n++)
                    acc[m][n] = __builtin_amdgcn_mfma_f32_16x16x32_bf16(af[m], bfr[n], acc[m][n], 0, 0, 0);
        }
    }
    for (int m = 0; m < 4; m++)
        for (int n = 0; n < 4; n++) {
            const int col = n0 + wn * 64 + n * 16 + lr;
            const float scl = (col < scale_below) ? 0.125f : 1.0f;
            const float bvv = bias[col];
            for (int j = 0; j < 4; j++) {
                const int row = m0 + wm * 64 + m * 16 + g * 4 + j;
                float v = (acc[m][n][j] + bvv) * scl;
                if (GELU) v = gelu_exact(v);
                if (OUTBF) ((unsigned short*)outp)[(size_t)row * N + col] = f2bf(v);
                else       ((float*)outp)[(size_t)row * N + col] = v;
            }
        }
}

// ---------------- V transpose: qkv[b][s][2304] (V at col 1536+h*64) -> vt[b][h][d][s] ----------------
__global__ __launch_bounds__(256) void vtrans_kernel(
    const unsigned short* __restrict__ qkv, unsigned short* __restrict__ vt)
{
    __shared__ unsigned short T[64][68];
    const int t = threadIdx.x;
    const int s0 = blockIdx.x * 64;
    const int h = blockIdx.y, b = blockIdx.z;
    const int r = t >> 2, seg = t & 3;
    const unsigned short* src = qkv + (size_t)(b * S_ + s0 + r) * QS_ + 1536 + h * HD_ + seg * 16;
    *reinterpret_cast<uint4*>(&T[r][seg * 16])     = *reinterpret_cast<const uint4*>(src);
    *reinterpret_cast<uint4*>(&T[r][seg * 16 + 8]) = *reinterpret_cast<const uint4*>(src + 8);
    __syncthreads();
    unsigned short tmp[16];
    for (int i = 0; i < 16; i++) tmp[i] = T[seg * 16 + i][r];
    unsigned short* dst = vt + ((size_t)(b * H_ + h) * HD_ + r) * S_ + s0 + seg * 16;
    *reinterpret_cast<uint4*>(dst)     = *reinterpret_cast<uint4*>(&tmp[0]);
    *reinterpret_cast<uint4*>(dst + 8) = *reinterpret_cast<uint4*>(&tmp[8]);
}

// ---------------- edge MLP + scatter fused ----------------
__global__ __launch_bounds__(256) void edge_proj_scatter_kernel(
    const float* __restrict__ ea, const float* __restrict__ W1, const float* __restrict__ b1,
    const float* __restrict__ W2, const float* __restrict__ b2,
    const int* __restrict__ ei, float* __restrict__ proj, int* __restrict__ winner)
{
    const int tid = blockIdx.x * 256 + threadIdx.x;
    const int e = tid / H_, h = tid - e * H_;
    const float a = ea[e];
    float s = 0.f;
    for (int j = 0; j < 16; j++) {
        const float tv = a * W1[h * 16 + j] + b1[h * 16 + j];
        s += gelu_exact(tv) * W2[h * 16 + j];
    }
    proj[tid] = s + b2[h];
    if (h == 0) {
        const int sn = ei[e], dn = ei[E_ + e];
        atomicMax(&winner[sn * S_ + dn], e);
    }
}

// ---------------- ebias[h][q][k] bf16 (vectorized: 4 k per thread) ----------------
__global__ __launch_bounds__(256) void ebias_kernel(
    const int* __restrict__ winner, const float* __restrict__ proj,
    unsigned short* __restrict__ ebias)
{
    const int q = blockIdx.x;
    const int t = threadIdx.x;
    const int k4 = t * 4;
    const int4 wv = *reinterpret_cast<const int4*>(&winner[q * S_ + k4]);
    for (int h = 0; h < H_; h++) {
        unsigned int lo = 0, hi = 0;
        if (wv.x >= 0) lo |= (unsigned int)f2bf(proj[(size_t)wv.x * H_ + h]);
        if (wv.y >= 0) lo |= ((unsigned int)f2bf(proj[(size_t)wv.y * H_ + h])) << 16;
        if (wv.z >= 0) hi |= (unsigned int)f2bf(proj[(size_t)wv.z * H_ + h]);
        if (wv.w >= 0) hi |= ((unsigned int)f2bf(proj[(size_t)wv.w * H_ + h])) << 16;
        uint2 val; val.x = lo; val.y = hi;
        *reinterpret_cast<uint2*>(&ebias[((size_t)h * S_ + q) * S_ + k4]) = val;
    }
}

// ---------------- mask bit-pack with per-block format self-detect ----------------
__global__ __launch_bounds__(256) void maskpack_kernel(
    const void* __restrict__ adj, unsigned int* __restrict__ mp)
{
    __shared__ unsigned int words[32];
    __shared__ int u8f;
    const int q = blockIdx.x, b = blockIdx.y;
    const int t = threadIdx.x;
    if (t < 32) words[t] = 0;
    if (t == 0) u8f = 0;
    __syncthreads();
    const unsigned int* row8 = (const unsigned int*)((const unsigned char*)adj + ((size_t)b * S_ + q) * S_);
    const unsigned int* row32 = (const unsigned int*)((const int*)adj + ((size_t)b * S_ + q) * S_);
    const unsigned int v = row8[t];
    if (v & 0xFF00FF00u) atomicOr(&u8f, 1);
    __syncthreads();
    if (u8f) {
        unsigned int nib = 0;
        if (v & 0x000000FFu) nib |= 1u;
        if (v & 0x0000FF00u) nib |= 2u;
        if (v & 0x00FF0000u) nib |= 4u;
        if (v & 0xFF000000u) nib |= 8u;
        if (nib) atomicOr(&words[t >> 3], nib << ((t & 7) * 4));
    } else {
        for (int i = 0; i < 4; i++) {
            const int k = i * 256 + t;
            if (row32[k]) atomicOr(&words[k >> 5], 1u << (k & 31));
        }
    }
    __syncthreads();
    if (t < 32) mp[((size_t)b * S_ + q) * 32 + t] = words[t];
}

// ---------------- MFMA flash attention, KV-split: block = (qt, sp, h, b) ----------------
__global__ __launch_bounds__(256) void attn_mfma_kernel(
    const unsigned short* __restrict__ qkv,   // Q col 0, K col 768, stride QS_
    const unsigned short* __restrict__ vt,    // [b][h][d][s]
    const unsigned short* __restrict__ ebias, // [h][q][k]
    const unsigned int* __restrict__ mp,      // [b][q][32]
    float* __restrict__ pacc,                 // [sp][bh][q][64]
    float2* __restrict__ pml)                 // [sp][bh][q]
{
    __shared__ unsigned short Ks[64][64];
    __shared__ unsigned short Vs[64][64];
    __shared__ unsigned short Eb[64][72];
    __shared__ unsigned int   Mw[64][2];
    __shared__ unsigned short Ps[4][16][64];
    const int t = threadIdx.x;
    const int w = t >> 6, l = t & 63;
    const int lr = l & 15, g = l >> 4;
    const int qt = blockIdx.x & 15, sp = blockIdx.x >> 4;
    const int q0 = qt * 64;
    const int h = blockIdx.y, b = blockIdx.z;
    const int bh = b * H_ + h;
    const size_t qbase = (size_t)b * S_ * QS_ + h * HD_;
    const size_t kbase = qbase + 768;
    const size_t vtbase = (size_t)bh * HD_ * S_;

    const int qrow = q0 + w * 16 + lr;
    const bf16x8 af0 = *reinterpret_cast<const bf16x8*>(qkv + qbase + (size_t)qrow * QS_ + g * 8);
    const bf16x8 af1 = *reinterpret_cast<const bf16x8*>(qkv + qbase + (size_t)qrow * QS_ + 32 + g * 8);

    float m_run[4], l_run[4];
    f32x4 acc[4] = {};
    for (int j = 0; j < 4; j++) { m_run[j] = -3.0e38f; l_run[j] = 0.f; }

    const int srow = t >> 2, sseg = t & 3;
    const int kt_beg = sp * (S_ / NSPLIT), kt_end = kt_beg + S_ / NSPLIT;
    for (int kt = kt_beg; kt < kt_end; kt += 64) {
        __syncthreads();
        {
            const unsigned short* ksrc = qkv + kbase + (size_t)(kt + srow) * QS_ + sseg * 16;
            *reinterpret_cast<uint4*>(&Ks[srow][SW(srow, sseg * 2)])     = *reinterpret_cast<const uint4*>(ksrc);
            *reinterpret_cast<uint4*>(&Ks[srow][SW(srow, sseg * 2 + 1)]) = *reinterpret_cast<const uint4*>(ksrc + 8);
            const unsigned short* vsrc = vt + vtbase + (size_t)srow * S_ + kt + sseg * 16;
            *reinterpret_cast<uint4*>(&Vs[srow][SW(srow, sseg * 2)])     = *reinterpret_cast<const uint4*>(vsrc);
            *reinterpret_cast<uint4*>(&Vs[srow][SW(srow, sseg * 2 + 1)]) = *reinterpret_cast<const uint4*>(vsrc + 8);
            const unsigned short* esrc = ebias + ((size_t)h * S_ + q0 + srow) * S_ + kt + sseg * 16;
            *reinterpret_cast<uint4*>(&Eb[srow][sseg * 16])     = *reinterpret_cast<const uint4*>(esrc);
            *reinterpret_cast<uint4*>(&Eb[srow][sseg * 16 + 8]) = *reinterpret_cast<const uint4*>(esrc + 8);
            if (t < 128) Mw[t >> 1][t & 1] = mp[((size_t)b * S_ + q0 + (t >> 1)) * 32 + (kt >> 5) + (t & 1)];
        }
        __syncthreads();
        f32x4 sc[4];
        for (int n = 0; n < 4; n++) {
            const int r = n * 16 + lr;
            const bf16x8 b0 = *reinterpret_cast<const bf16x8*>(&Ks[r][SW(r, g)]);
            const bf16x8 b1 = *reinterpret_cast<const bf16x8*>(&Ks[r][SW(r, 4 + g)]);
            f32x4 z = {};
            z = __builtin_amdgcn_mfma_f32_16x16x32_bf16(af0, b0, z, 0, 0, 0);
            z = __builtin_amdgcn_mfma_f32_16x16x32_bf16(af1, b1, z, 0, 0, 0);
            sc[n] = z;
        }
        float tmax[4] = {-3.0e38f, -3.0e38f, -3.0e38f, -3.0e38f};
        for (int n = 0; n < 4; n++) {
            for (int j = 0; j < 4; j++) {
                const int rq = w * 16 + g * 4 + j;
                const unsigned int word = Mw[rq][n >> 1];
                const bool msk = (word >> ((n & 1) * 16 + lr)) & 1;
                float sval;
                if (msk) sval = sc[n][j] + bf2f(Eb[rq][n * 16 + lr]);
                else sval = -1e9f;
                sc[n][j] = sval;
                tmax[j] = fmaxf(tmax[j], sval);
            }
        }
        float pscale[4];
        for (int j = 0; j < 4; j++) {
            float tm = tmax[j];
            tm = fmaxf(tm, __shfl_xor(tm, 1));
            tm = fmaxf(tm, __shfl_xor(tm, 2));
            tm = fmaxf(tm, __shfl_xor(tm, 4));
            tm = fmaxf(tm, __shfl_xor(tm, 8));
            const float mnew = fmaxf(m_run[j], tm);
            pscale[j] = __expf(m_run[j] - mnew);
            m_run[j] = mnew;
            l_run[j] *= pscale[j];
        }
        float psum[4] = {0.f, 0.f, 0.f, 0.f};
        for (int n = 0; n < 4; n++) {
            for (int j = 0; j < 4; j++) {
                const float p = __expf(sc[n][j] - m_run[j]);
                psum[j] += p;
                const int row = g * 4 + j;
                Ps[w][row][SW(row, n * 2 + (lr >> 3)) + (lr & 7)] = f2bf(p);
            }
        }
        for (int j = 0; j < 4; j++) {
            float s = psum[j];
            s += __shfl_xor(s, 1); s += __shfl_xor(s, 2);
            s += __shfl_xor(s, 4); s += __shfl_xor(s, 8);
            l_run[j] += s;
            for (int n2 = 0; n2 < 4; n2++) acc[n2][j] *= pscale[j];
        }
        const bf16x8 pa0 = *reinterpret_cast<const bf16x8*>(&Ps[w][lr][SW(lr, g)]);
        const bf16x8 pa1 = *reinterpret_cast<const bf16x8*>(&Ps[w][lr][SW(lr, 4 + g)]);
        for (int n2 = 0; n2 < 4; n2++) {
            const int r = n2 * 16 + lr;
            const bf16x8 vb0 = *reinterpret_cast<const bf16x8*>(&Vs[r][SW(r, g)]);
            const bf16x8 vb1 = *reinterpret_cast<const bf16x8*>(&Vs[r][SW(r, 4 + g)]);
            acc[n2] = __builtin_amdgcn_mfma_f32_16x16x32_bf16(pa0, vb0, acc[n2], 0, 0, 0);
            acc[n2] = __builtin_amdgcn_mfma_f32_16x16x32_bf16(pa1, vb1, acc[n2], 0, 0, 0);
        }
    }
    // ---- partial epilogue ----
    const size_t prow = (size_t)sp * BHS + (size_t)bh * S_;
    for (int j = 0; j < 4; j++) {
        const int qg = q0 + w * 16 + g * 4 + j;
        for (int n2 = 0; n2 < 4; n2++)
            pacc[(prow + qg) * 64 + n2 * 16 + lr] = acc[n2][j];
        if (lr == 0) { float2 v; v.x = m_run[j]; v.y = l_run[j]; pml[prow + qg] = v; }
    }
}

// ---------------- combine NSPLIT partials -> attnb bf16 [b][q][768] ----------------
__global__ __launch_bounds__(256) void attn_combine_kernel(
    const float* __restrict__ pacc, const float2* __restrict__ pml,
    unsigned short* __restrict__ attnb)
{
    const int idx = (blockIdx.x * 256 + threadIdx.x) * 4;  // grid covers BHS*64
    const int r = idx >> 6, d = idx & 63;
    float2 ml[NSPLIT];
    float mx = -3.0e38f;
    for (int s = 0; s < NSPLIT; s++) {
        ml[s] = pml[(size_t)s * BHS + r];
        mx = fmaxf(mx, ml[s].x);
    }
    float wgt[NSPLIT], L = 0.f;
    for (int s = 0; s < NSPLIT; s++) {
        wgt[s] = __expf(ml[s].x - mx);
        L += ml[s].y * wgt[s];
    }
    const float inv = (L > 0.f) ? 1.f / L : 0.f;
    float4 o = {0.f, 0.f, 0.f, 0.f};
    for (int s = 0; s < NSPLIT; s++) {
        const float4 a = *reinterpret_cast<const float4*>(&pacc[((size_t)s * BHS + r) * 64 + d]);
        o.x += a.x * wgt[s]; o.y += a.y * wgt[s];
        o.z += a.z * wgt[s]; o.w += a.w * wgt[s];
    }
    const int bh = r >> 10, q = r & 1023;
    const int b = bh / H_, h = bh - b * H_;
    ushort4 ov;
    ov.x = f2bf(o.x * inv); ov.y = f2bf(o.y * inv);
    ov.z = f2bf(o.z * inv); ov.w = f2bf(o.w * inv);
    *reinterpret_cast<ushort4*>(&attnb[((size_t)(b * S_ + q)) * D_ + h * HD_ + d]) = ov;
}

extern "C" void kernel_launch(void* const* d_in, const int* in_sizes, int n_in,
                              void* d_out, int out_size, void* d_ws, size_t ws_size,
                              hipStream_t stream)
{
    const float* x    = (const float*)d_in[0];
    const void*  adj  = d_in[1];
    const float* ea   = (const float*)d_in[2];
    const int*   ei   = (const int*)d_in[3];
    const float* g1   = (const float*)d_in[4];
    const float* bn1  = (const float*)d_in[5];
    const float* Wq   = (const float*)d_in[6];
    const float* bq   = (const float*)d_in[7];
    const float* Wk   = (const float*)d_in[8];
    const float* bk   = (const float*)d_in[9];
    const float* Wv   = (const float*)d_in[10];
    const float* bv   = (const float*)d_in[11];
    const float* Wo   = (const float*)d_in[12];
    const float* bo   = (const float*)d_in[13];
    const float* g2   = (const float*)d_in[14];
    const float* bn2  = (const float*)d_in[15];
    const float* W1   = (const float*)d_in[16];
    const float* mb1  = (const float*)d_in[17];
    const float* W2   = (const float*)d_in[18];
    const float* mb2  = (const float*)d_in[19];
    const float* epW1 = (const float*)d_in[20];
    const float* epb1 = (const float*)d_in[21];
    const float* epW2 = (const float*)d_in[22];
    const float* epb2 = (const float*)d_in[23];

    char* ws = (char*)d_ws;
    size_t off = 0;
    auto carve = [&](size_t bytes) -> void* {
        void* p = ws + off;
        off += (bytes + 255) & ~(size_t)255;
        return p;
    };
    unsigned short* wqkvt = (unsigned short*)carve((size_t)QS_ * D_ * 2);
    unsigned short* wot   = (unsigned short*)carve((size_t)D_ * D_ * 2);
    unsigned short* w1t   = (unsigned short*)carve((size_t)FF_ * D_ * 2);
    unsigned short* w2t   = (unsigned short*)carve((size_t)D_ * FF_ * 2);
    float*          bqkv  = (float*)carve((size_t)QS_ * 4);
    float*          proj  = (float*)carve((size_t)E_ * H_ * 4);
    int*            winner= (int*)carve((size_t)S_ * S_ * 4);
    unsigned short* ebias = (unsigned short*)carve((size_t)H_ * S_ * S_ * 2);  // 25.2 MB, reused as W2 partials
    unsigned int*   mpk   = (unsigned int*)carve((size_t)B_ * S_ * 32 * 4);
    unsigned short* nxb   = (unsigned short*)carve((size_t)B_ * S_ * D_ * 2);  // reused as ln2b
    unsigned short* attnb = (unsigned short*)carve((size_t)B_ * S_ * D_ * 2);
    unsigned short* qkv   = (unsigned short*)carve((size_t)B_ * S_ * QS_ * 2);
    unsigned short* vtb   = (unsigned short*)carve((size_t)B_ * S_ * D_ * 2);
    float*          x2f   = (float*)carve((size_t)B_ * S_ * D_ * 4);
    float*          pacc  = (float*)carve((size_t)NSPLIT * BHS * 64 * 4);      // 25.2 MB
    float2*         pml   = (float2*)carve((size_t)NSPLIT * BHS * 8);
    unsigned short* ln2b = nxb;
    unsigned short* hb   = qkv;           // [2048][3072] bf16 aliases qkv+vtb (dead after attn)
    float*          pw2  = (float*)ebias; // W2 split-K partials alias ebias (dead after attn)

    const int M = B_ * S_;  // 2048

    // fast winner init (was 40us runtime fillBuffer)
    fill_winner_kernel<<<(S_ * S_) / 1024, 256, 0, stream>>>(winner);

    // all weight transposes + bias concat (1 launch)
    wtrans_all_kernel<<<dim3(96, 24, 6), 256, 0, stream>>>(
        Wq, Wk, Wv, Wo, W1, W2, wqkvt, wot, w1t, w2t, bq, bk, bv, bqkv);

    // LN1
    ln_kernel<<<M, 256, 0, stream>>>(x, g1, bn1, nxb);

    // fused QKV (bf16 out, Q cols scaled by 0.125)
    gemm128_kernel<false, true><<<dim3(QS_ / 128, M / 128), 256, 0, stream>>>(
        nxb, wqkvt, bqkv, qkv, M, QS_, D_, 768);

    // V transpose
    vtrans_kernel<<<dim3(S_ / 64, H_, B_), 256, 0, stream>>>(qkv, vtb);

    // edge bias pipeline
    edge_proj_scatter_kernel<<<(E_ * H_) / 256, 256, 0, stream>>>(
        ea, epW1, epb1, epW2, epb2, ei, proj, winner);
    ebias_kernel<<<S_, 256, 0, stream>>>(winner, proj, ebias);
    maskpack_kernel<<<dim3(S_, B_), 256, 0, stream>>>(adj, mpk);

    // attention (KV-split x4) + combine
    attn_mfma_kernel<<<dim3(16 * NSPLIT, H_, B_), 256, 0, stream>>>(
        qkv, vtb, ebias, mpk, pacc, pml);
    attn_combine_kernel<<<(BHS * 64) / 1024, 256, 0, stream>>>(pacc, pml, attnb);

    // Wo + residual(x) -> x2 (f32)
    gemm_kernel<true, false><<<dim3(D_ / 64, M / 64), 256, 0, stream>>>(
        attnb, wot, bo, x, x2f, M, D_, D_);

    // LN2
    ln_kernel<<<M, 256, 0, stream>>>(x2f, g2, bn2, ln2b);

    // MLP
    gemm128_kernel<true, true><<<dim3(FF_ / 128, M / 128), 256, 0, stream>>>(
        ln2b, w1t, mb1, hb, M, FF_, D_, 0);
    gemm_splitk_kernel<<<dim3(D_ / 64, M / 64, 2), 256, 0, stream>>>(
        hb, w2t, pw2, M, D_, FF_, FF_ / 2);
    w2_reduce_kernel<<<(M * D_) / 1024, 256, 0, stream>>>(pw2, x2f, mb2, (float*)d_out);
}

// Round 6
// 191.120 us; speedup vs baseline: 1.0853x; 1.0853x over previous
//
#include <hip/hip_runtime.h>
#include <hip/hip_bf16.h>

#define B_ 2
#define S_ 1024
#define D_ 768
#define H_ 12
#define HD_ 64
#define FF_ 3072
#define E_ 32768
#define QS_ 2304   // fused QKV row stride
#define NSPLIT 2   // attention KV splits
#define NSPLIT_W2 4
#define BHS (B_ * H_ * S_)   // 24576 partial rows per split

typedef short bf16x8 __attribute__((ext_vector_type(8)));
typedef float f32x4 __attribute__((ext_vector_type(4)));

// XOR swizzle: 8-elem seg s of row r lives at elem offset SW(r,s)
#define SW(row, seg) ((((seg) ^ ((row) & 7)) * 8))

__device__ __forceinline__ unsigned short f2bf(float f) {
    __hip_bfloat16 h = __float2bfloat16(f);
    return __builtin_bit_cast(unsigned short, h);
}
__device__ __forceinline__ float bf2f(unsigned short u) {
    unsigned int v = ((unsigned int)u) << 16;
    return __builtin_bit_cast(float, v);
}
__device__ __forceinline__ float gelu_exact(float x) {
    return 0.5f * x * (1.0f + erff(x * 0.70710678118654752f));
}
// async global->LDS, 16B per lane; LDS dest is wave-uniform base + lane*16
__device__ __forceinline__ void gload_lds16(const unsigned short* g, unsigned short* l) {
    __builtin_amdgcn_global_load_lds((const __attribute__((address_space(1))) void*)g,
                                     (__attribute__((address_space(3))) void*)l, 16, 0, 0);
}

// ---------------- LayerNorm: f32 in -> bf16 out (row = 768) ----------------
__global__ __launch_bounds__(256) void ln_kernel(
    const float* __restrict__ x, const float* __restrict__ g,
    const float* __restrict__ b, unsigned short* __restrict__ out)
{
    const int row = blockIdx.x;
    const int t = threadIdx.x;
    const float* xr = x + (size_t)row * D_;
    float v0 = xr[t], v1 = xr[t + 256], v2 = xr[t + 512];
    float s = v0 + v1 + v2, s2 = v0 * v0 + v1 * v1 + v2 * v2;
    for (int m = 32; m; m >>= 1) { s += __shfl_xor(s, m); s2 += __shfl_xor(s2, m); }
    __shared__ float red[8];
    const int w = t >> 6;
    if ((t & 63) == 0) { red[w] = s; red[4 + w] = s2; }
    __syncthreads();
    s = red[0] + red[1] + red[2] + red[3];
    s2 = red[4] + red[5] + red[6] + red[7];
    const float mean = s * (1.f / D_);
    const float var = s2 * (1.f / D_) - mean * mean;
    const float rstd = rsqrtf(var + 1e-5f);
    unsigned short* orow = out + (size_t)row * D_;
    orow[t]       = f2bf((v0 - mean) * rstd * g[t]       + b[t]);
    orow[t + 256] = f2bf((v1 - mean) * rstd * g[t + 256] + b[t + 256]);
    orow[t + 512] = f2bf((v2 - mean) * rstd * g[t + 512] + b[t + 512]);
}

// ------------- all weight transposes + bias concat in ONE launch -------------
__global__ __launch_bounds__(256) void wtrans_all_kernel(
    const float* __restrict__ Wq, const float* __restrict__ Wk, const float* __restrict__ Wv,
    const float* __restrict__ Wo, const float* __restrict__ W1, const float* __restrict__ W2,
    unsigned short* __restrict__ wqkvt, unsigned short* __restrict__ wot,
    unsigned short* __restrict__ w1t, unsigned short* __restrict__ w2t,
    const float* __restrict__ bq, const float* __restrict__ bk, const float* __restrict__ bv,
    float* __restrict__ bqkv)
{
    const int z = blockIdx.z;
    const float* src; unsigned short* dst; int K, N, nb, kb;
    if (z < 4) {
        if (blockIdx.x >= 24 || blockIdx.y >= 24) return;
        K = 768; N = 768; nb = blockIdx.x * 32; kb = blockIdx.y * 32;
        src = (z == 0) ? Wq : (z == 1) ? Wk : (z == 2) ? Wv : Wo;
        dst = (z == 3) ? wot : wqkvt + (size_t)z * 768 * 768;
    } else if (z == 4) {
        if (blockIdx.y >= 24) return;
        K = 768; N = 3072; nb = blockIdx.x * 32; kb = blockIdx.y * 32;
        src = W1; dst = w1t;
    } else {
        if (blockIdx.y >= 24) return;
        K = 3072; N = 768; nb = blockIdx.y * 32; kb = blockIdx.x * 32;
        src = W2; dst = w2t;
    }
    __shared__ float tile[32][33];
    const int tx = threadIdx.x & 31, ty = threadIdx.x >> 5;
    for (int r = 0; r < 32; r += 8)
        tile[ty + r][tx] = src[(size_t)(kb + ty + r) * N + nb + tx];
    __syncthreads();
    for (int r = 0; r < 32; r += 8)
        dst[(size_t)(nb + ty + r) * K + kb + tx] = f2bf(tile[tx][ty + r]);
    if (z == 0 && blockIdx.x == 0 && blockIdx.y == 0) {
        for (int i = threadIdx.x; i < QS_; i += 256)
            bqkv[i] = (i < 768) ? bq[i] : (i < 1536) ? bk[i - 768] : bv[i - 1536];
    }
}

// ---------------- 64x64 GEMM (Wo): C = (A @ Bt^T + bias) [+res] ----------------
template<bool RES, bool OUTBF>
__global__ __launch_bounds__(256) void gemm_kernel(
    const unsigned short* __restrict__ A, const unsigned short* __restrict__ Bt,
    const float* __restrict__ bias, const float* __restrict__ res,
    void* __restrict__ outp, int M, int N, int K)
{
    __shared__ unsigned short As[64][40];
    __shared__ unsigned short Bs[64][40];
    const int m0 = blockIdx.y * 64, n0 = blockIdx.x * 64;
    const int t = threadIdx.x;
    const int w = t >> 6, l = t & 63;
    const int wm = w >> 1, wn = w & 1;
    const int r = l & 15, g = l >> 4;
    const int srow = t >> 2, sseg = t & 3;
    f32x4 acc[2][2] = {};
    for (int k0 = 0; k0 < K; k0 += 32) {
        __syncthreads();
        const uint4 av = *reinterpret_cast<const uint4*>(A + (size_t)(m0 + srow) * K + k0 + sseg * 8);
        *reinterpret_cast<uint4*>(&As[srow][sseg * 8]) = av;
        const uint4 bv = *reinterpret_cast<const uint4*>(Bt + (size_t)(n0 + srow) * K + k0 + sseg * 8);
        *reinterpret_cast<uint4*>(&Bs[srow][sseg * 8]) = bv;
        __syncthreads();
        bf16x8 af[2], bfr[2];
        af[0]  = *reinterpret_cast<const bf16x8*>(&As[wm * 32 + r][g * 8]);
        af[1]  = *reinterpret_cast<const bf16x8*>(&As[wm * 32 + 16 + r][g * 8]);
        bfr[0] = *reinterpret_cast<const bf16x8*>(&Bs[wn * 32 + r][g * 8]);
        bfr[1] = *reinterpret_cast<const bf16x8*>(&Bs[wn * 32 + 16 + r][g * 8]);
        for (int m = 0; m < 2; m++)
            for (int n = 0; n < 2; n++)
                acc[m][n] = __builtin_amdgcn_mfma_f32_16x16x32_bf16(af[m], bfr[n], acc[m][n], 0, 0, 0);
    }
    for (int m = 0; m < 2; m++)
        for (int n = 0; n < 2; n++) {
            const int col = n0 + wn * 32 + n * 16 + r;
            const float bvv = bias[col];
            for (int j = 0; j < 4; j++) {
                const int row = m0 + wm * 32 + m * 16 + g * 4 + j;
                float v = acc[m][n][j] + bvv;
                if (RES) v += res[(size_t)row * N + col];
                if (OUTBF) ((unsigned short*)outp)[(size_t)row * N + col] = f2bf(v);
                else       ((float*)outp)[(size_t)row * N + col] = v;
            }
        }
}

// ---------------- 128x128 GEMM, BK=64, global_load_lds + pre-swizzled source ----------------
// SPLITK: partial f32 out [z][M][N]; else (bias, scale_below cols *0.125, GELU, bf16/f32 out)
template<bool GELU, bool OUTBF, bool SPLITK>
__global__ __launch_bounds__(256) void gemm128_kernel(
    const unsigned short* __restrict__ A, const unsigned short* __restrict__ Bt,
    const float* __restrict__ bias, void* __restrict__ outp,
    int M, int N, int K, int klen, int scale_below)
{
    __shared__ unsigned short As[128][64];
    __shared__ unsigned short Bs[128][64];
    const int m0 = blockIdx.y * 128, n0 = blockIdx.x * 128;
    const int t = threadIdx.x;
    const int w = t >> 6, l = t & 63;
    const int wm = w >> 1, wn = w & 1;
    const int lr = l & 15, g = l >> 4;
    const int lrow8 = l >> 3;            // row within 8-row chunk
    const int lseg = (l & 7) ^ lrow8;    // pre-swizzled global source seg
    const int kbeg = SPLITK ? blockIdx.z * klen : 0;
    const int kend = SPLITK ? kbeg + klen : K;
    f32x4 acc[4][4] = {};
    for (int k0 = kbeg; k0 < kend; k0 += 64) {
        __syncthreads();
        for (int j = 0; j < 4; j++) {
            const int q = w * 4 + j;           // chunk 0..15 (8 rows each)
            const int row = q * 8 + lrow8;
            gload_lds16(A  + (size_t)(m0 + row) * K + k0 + lseg * 8, &As[q * 8][0]);
            gload_lds16(Bt + (size_t)(n0 + row) * K + k0 + lseg * 8, &Bs[q * 8][0]);
        }
        __syncthreads();
        for (int kk = 0; kk < 2; kk++) {
            bf16x8 af[4], bfr[4];
            for (int m = 0; m < 4; m++) {
                const int r = wm * 64 + m * 16 + lr;
                af[m] = *reinterpret_cast<const bf16x8*>(&As[r][SW(r, kk * 4 + g)]);
            }
            for (int n = 0; n < 4; n++) {
                const int r = wn * 64 + n * 16 + lr;
                bfr[n] = *reinterpret_cast<const bf16x8*>(&Bs[r][SW(r, kk * 4 + g)]);
            }
            for (int m = 0; m < 4; m++)
                for (int n = 0; n < 4; n++)
                    acc[m][n] = __builtin_amdgcn_mfma_f32_16x16x32_bf16(af[m], bfr[n], acc[m][n], 0, 0, 0);
        }
    }
    if (SPLITK) {
        float* op = (float*)outp + (size_t)blockIdx.z * M * N;
        for (int m = 0; m < 4; m++)
            for (int n = 0; n < 4; n++) {
                const int col = n0 + wn * 64 + n * 16 + lr;
                for (int j = 0; j < 4; j++) {
                    const int row = m0 + wm * 64 + m * 16 + g * 4 + j;
                    op[(size_t)row * N + col] = acc[m][n][j];
                }
            }
    } else {
        for (int m = 0; m < 4; m++)
            for (int n = 0; n < 4; n++) {
                const int col = n0 + wn * 64 + n * 16 + lr;
                const float scl = (col < scale_below) ? 0.125f : 1.0f;
                const float bvv = bias[col];
                for (int j = 0; j < 4; j++) {
                    const int row = m0 + wm * 64 + m * 16 + g * 4 + j;
                    float v = (acc[m][n][j] + bvv) * scl;
                    if (GELU) v = gelu_exact(v);
                    if (OUTBF) ((unsigned short*)outp)[(size_t)row * N + col] = f2bf(v);
                    else       ((float*)outp)[(size_t)row * N + col] = v;
                }
            }
    }
}

// ---------------- W2 reduce: d_out = x2 + b2 + sum_z part[z] ----------------
__global__ __launch_bounds__(256) void w2_reduce_kernel(
    const float* __restrict__ part, const float* __restrict__ x2,
    const float* __restrict__ b2, float* __restrict__ out)
{
    const int idx = (blockIdx.x * 256 + threadIdx.x) * 4;
    const int col = idx % D_;
    const float4 xr = *reinterpret_cast<const float4*>(&x2[idx]);
    const float4 bb = *reinterpret_cast<const float4*>(&b2[col]);
    float4 o;
    o.x = xr.x + bb.x; o.y = xr.y + bb.y; o.z = xr.z + bb.z; o.w = xr.w + bb.w;
    for (int s = 0; s < NSPLIT_W2; s++) {
        const float4 p = *reinterpret_cast<const float4*>(&part[(size_t)s * B_ * S_ * D_ + idx]);
        o.x += p.x; o.y += p.y; o.z += p.z; o.w += p.w;
    }
    *reinterpret_cast<float4*>(&out[idx]) = o;
}

// ---------------- V transpose: qkv[b][s][2304] (V at col 1536+h*64) -> vt[b][h][d][s] ----------------
__global__ __launch_bounds__(256) void vtrans_kernel(
    const unsigned short* __restrict__ qkv, unsigned short* __restrict__ vt)
{
    __shared__ unsigned short T[64][68];
    const int t = threadIdx.x;
    const int s0 = blockIdx.x * 64;
    const int h = blockIdx.y, b = blockIdx.z;
    const int r = t >> 2, seg = t & 3;
    const unsigned short* src = qkv + (size_t)(b * S_ + s0 + r) * QS_ + 1536 + h * HD_ + seg * 16;
    *reinterpret_cast<uint4*>(&T[r][seg * 16])     = *reinterpret_cast<const uint4*>(src);
    *reinterpret_cast<uint4*>(&T[r][seg * 16 + 8]) = *reinterpret_cast<const uint4*>(src + 8);
    __syncthreads();
    unsigned short tmp[16];
    for (int i = 0; i < 16; i++) tmp[i] = T[seg * 16 + i][r];
    unsigned short* dst = vt + ((size_t)(b * H_ + h) * HD_ + r) * S_ + s0 + seg * 16;
    *reinterpret_cast<uint4*>(dst)     = *reinterpret_cast<uint4*>(&tmp[0]);
    *reinterpret_cast<uint4*>(dst + 8) = *reinterpret_cast<uint4*>(&tmp[8]);
}

// ---------------- edge MLP + scatter fused ----------------
__global__ __launch_bounds__(256) void edge_proj_scatter_kernel(
    const float* __restrict__ ea, const float* __restrict__ W1, const float* __restrict__ b1,
    const float* __restrict__ W2, const float* __restrict__ b2,
    const int* __restrict__ ei, float* __restrict__ proj, int* __restrict__ winner)
{
    const int tid = blockIdx.x * 256 + threadIdx.x;
    const int e = tid / H_, h = tid - e * H_;
    const float a = ea[e];
    float s = 0.f;
    for (int j = 0; j < 16; j++) {
        const float tv = a * W1[h * 16 + j] + b1[h * 16 + j];
        s += gelu_exact(tv) * W2[h * 16 + j];
    }
    proj[tid] = s + b2[h];
    if (h == 0) {
        const int sn = ei[e], dn = ei[E_ + e];
        atomicMax(&winner[sn * S_ + dn], e);
    }
}

// ---------------- ebias[h][q][k] bf16 (vectorized: 4 k per thread) ----------------
__global__ __launch_bounds__(256) void ebias_kernel(
    const int* __restrict__ winner, const float* __restrict__ proj,
    unsigned short* __restrict__ ebias)
{
    const int q = blockIdx.x;
    const int t = threadIdx.x;
    const int k4 = t * 4;
    const int4 wv = *reinterpret_cast<const int4*>(&winner[q * S_ + k4]);
    for (int h = 0; h < H_; h++) {
        unsigned int lo = 0, hi = 0;
        if (wv.x >= 0) lo |= (unsigned int)f2bf(proj[(size_t)wv.x * H_ + h]);
        if (wv.y >= 0) lo |= ((unsigned int)f2bf(proj[(size_t)wv.y * H_ + h])) << 16;
        if (wv.z >= 0) hi |= (unsigned int)f2bf(proj[(size_t)wv.z * H_ + h]);
        if (wv.w >= 0) hi |= ((unsigned int)f2bf(proj[(size_t)wv.w * H_ + h])) << 16;
        uint2 val; val.x = lo; val.y = hi;
        *reinterpret_cast<uint2*>(&ebias[((size_t)h * S_ + q) * S_ + k4]) = val;
    }
}

// ---------------- mask bit-pack (+winner -1 fill on y==0) ----------------
__global__ __launch_bounds__(256) void maskpack_kernel(
    const void* __restrict__ adj, unsigned int* __restrict__ mp, int* __restrict__ winner)
{
    const int q = blockIdx.x, b = blockIdx.y;
    const int t = threadIdx.x;
    if (b == 0) {
        int4 v; v.x = -1; v.y = -1; v.z = -1; v.w = -1;
        reinterpret_cast<int4*>(winner)[q * 256 + t] = v;
    }
    __shared__ unsigned int words[32];
    __shared__ int u8f;
    if (t < 32) words[t] = 0;
    if (t == 0) u8f = 0;
    __syncthreads();
    const unsigned int* row8 = (const unsigned int*)((const unsigned char*)adj + ((size_t)b * S_ + q) * S_);
    const unsigned int* row32 = (const unsigned int*)((const int*)adj + ((size_t)b * S_ + q) * S_);
    const unsigned int v = row8[t];
    if (v & 0xFF00FF00u) atomicOr(&u8f, 1);
    __syncthreads();
    if (u8f) {
        unsigned int nib = 0;
        if (v & 0x000000FFu) nib |= 1u;
        if (v & 0x0000FF00u) nib |= 2u;
        if (v & 0x00FF0000u) nib |= 4u;
        if (v & 0xFF000000u) nib |= 8u;
        if (nib) atomicOr(&words[t >> 3], nib << ((t & 7) * 4));
    } else {
        for (int i = 0; i < 4; i++) {
            const int k = i * 256 + t;
            if (row32[k]) atomicOr(&words[k >> 5], 1u << (k & 31));
        }
    }
    __syncthreads();
    if (t < 32) mp[((size_t)b * S_ + q) * 32 + t] = words[t];
}

// ---------------- MFMA flash attention, KV-split: block = (qt, sp, h, b) ----------------
__global__ __launch_bounds__(256) void attn_mfma_kernel(
    const unsigned short* __restrict__ qkv,   // Q col 0, K col 768, stride QS_
    const unsigned short* __restrict__ vt,    // [b][h][d][s]
    const unsigned short* __restrict__ ebias, // [h][q][k]
    const unsigned int* __restrict__ mp,      // [b][q][32]
    float* __restrict__ pacc,                 // [sp][bh][q][64]
    float2* __restrict__ pml)                 // [sp][bh][q]
{
    __shared__ unsigned short Ks[64][64];
    __shared__ unsigned short Vs[64][64];
    __shared__ unsigned short Eb[64][72];
    __shared__ unsigned int   Mw[64][2];
    __shared__ unsigned short Ps[4][16][64];
    const int t = threadIdx.x;
    const int w = t >> 6, l = t & 63;
    const int lr = l & 15, g = l >> 4;
    const int qt = blockIdx.x & 15, sp = blockIdx.x >> 4;
    const int q0 = qt * 64;
    const int h = blockIdx.y, b = blockIdx.z;
    const int bh = b * H_ + h;
    const size_t qbase = (size_t)b * S_ * QS_ + h * HD_;
    const size_t kbase = qbase + 768;
    const size_t vtbase = (size_t)bh * HD_ * S_;

    const int qrow = q0 + w * 16 + lr;
    const bf16x8 af0 = *reinterpret_cast<const bf16x8*>(qkv + qbase + (size_t)qrow * QS_ + g * 8);
    const bf16x8 af1 = *reinterpret_cast<const bf16x8*>(qkv + qbase + (size_t)qrow * QS_ + 32 + g * 8);

    float m_run[4], l_run[4];
    f32x4 acc[4] = {};
    for (int j = 0; j < 4; j++) { m_run[j] = -3.0e38f; l_run[j] = 0.f; }

    const int srow = t >> 2, sseg = t & 3;
    const int kt_beg = sp * (S_ / NSPLIT), kt_end = kt_beg + S_ / NSPLIT;
    for (int kt = kt_beg; kt < kt_end; kt += 64) {
        __syncthreads();
        {
            const unsigned short* ksrc = qkv + kbase + (size_t)(kt + srow) * QS_ + sseg * 16;
            *reinterpret_cast<uint4*>(&Ks[srow][SW(srow, sseg * 2)])     = *reinterpret_cast<const uint4*>(ksrc);
            *reinterpret_cast<uint4*>(&Ks[srow][SW(srow, sseg * 2 + 1)]) = *reinterpret_cast<const uint4*>(ksrc + 8);
            const unsigned short* vsrc = vt + vtbase + (size_t)srow * S_ + kt + sseg * 16;
            *reinterpret_cast<uint4*>(&Vs[srow][SW(srow, sseg * 2)])     = *reinterpret_cast<const uint4*>(vsrc);
            *reinterpret_cast<uint4*>(&Vs[srow][SW(srow, sseg * 2 + 1)]) = *reinterpret_cast<const uint4*>(vsrc + 8);
            const unsigned short* esrc = ebias + ((size_t)h * S_ + q0 + srow) * S_ + kt + sseg * 16;
            *reinterpret_cast<uint4*>(&Eb[srow][sseg * 16])     = *reinterpret_cast<const uint4*>(esrc);
            *reinterpret_cast<uint4*>(&Eb[srow][sseg * 16 + 8]) = *reinterpret_cast<const uint4*>(esrc + 8);
            if (t < 128) Mw[t >> 1][t & 1] = mp[((size_t)b * S_ + q0 + (t >> 1)) * 32 + (kt >> 5) + (t & 1)];
        }
        __syncthreads();
        f32x4 sc[4];
        for (int n = 0; n < 4; n++) {
            const int r = n * 16 + lr;
            const bf16x8 b0 = *reinterpret_cast<const bf16x8*>(&Ks[r][SW(r, g)]);
            const bf16x8 b1 = *reinterpret_cast<const bf16x8*>(&Ks[r][SW(r, 4 + g)]);
            f32x4 z = {};
            z = __builtin_amdgcn_mfma_f32_16x16x32_bf16(af0, b0, z, 0, 0, 0);
            z = __builtin_amdgcn_mfma_f32_16x16x32_bf16(af1, b1, z, 0, 0, 0);
            sc[n] = z;
        }
        float tmax[4] = {-3.0e38f, -3.0e38f, -3.0e38f, -3.0e38f};
        for (int n = 0; n < 4; n++) {
            for (int j = 0; j < 4; j++) {
                const int rq = w * 16 + g * 4 + j;
                const unsigned int word = Mw[rq][n >> 1];
                const bool msk = (word >> ((n & 1) * 16 + lr)) & 1;
                float sval;
                if (msk) sval = sc[n][j] + bf2f(Eb[rq][n * 16 + lr]);
                else sval = -1e9f;
                sc[n][j] = sval;
                tmax[j] = fmaxf(tmax[j], sval);
            }
        }
        float pscale[4];
        for (int j = 0; j < 4; j++) {
            float tm = tmax[j];
            tm = fmaxf(tm, __shfl_xor(tm, 1));
            tm = fmaxf(tm, __shfl_xor(tm, 2));
            tm = fmaxf(tm, __shfl_xor(tm, 4));
            tm = fmaxf(tm, __shfl_xor(tm, 8));
            const float mnew = fmaxf(m_run[j], tm);
            pscale[j] = __expf(m_run[j] - mnew);
            m_run[j] = mnew;
            l_run[j] *= pscale[j];
        }
        float psum[4] = {0.f, 0.f, 0.f, 0.f};
        for (int n = 0; n < 4; n++) {
            for (int j = 0; j < 4; j++) {
                const float p = __expf(sc[n][j] - m_run[j]);
                psum[j] += p;
                const int row = g * 4 + j;
                Ps[w][row][SW(row, n * 2 + (lr >> 3)) + (lr & 7)] = f2bf(p);
            }
        }
        for (int j = 0; j < 4; j++) {
            float s = psum[j];
            s += __shfl_xor(s, 1); s += __shfl_xor(s, 2);
            s += __shfl_xor(s, 4); s += __shfl_xor(s, 8);
            l_run[j] += s;
            for (int n2 = 0; n2 < 4; n2++) acc[n2][j] *= pscale[j];
        }
        const bf16x8 pa0 = *reinterpret_cast<const bf16x8*>(&Ps[w][lr][SW(lr, g)]);
        const bf16x8 pa1 = *reinterpret_cast<const bf16x8*>(&Ps[w][lr][SW(lr, 4 + g)]);
        for (int n2 = 0; n2 < 4; n2++) {
            const int r = n2 * 16 + lr;
            const bf16x8 vb0 = *reinterpret_cast<const bf16x8*>(&Vs[r][SW(r, g)]);
            const bf16x8 vb1 = *reinterpret_cast<const bf16x8*>(&Vs[r][SW(r, 4 + g)]);
            acc[n2] = __builtin_amdgcn_mfma_f32_16x16x32_bf16(pa0, vb0, acc[n2], 0, 0, 0);
            acc[n2] = __builtin_amdgcn_mfma_f32_16x16x32_bf16(pa1, vb1, acc[n2], 0, 0, 0);
        }
    }
    // ---- partial epilogue ----
    const size_t prow = (size_t)sp * BHS + (size_t)bh * S_;
    for (int j = 0; j < 4; j++) {
        const int qg = q0 + w * 16 + g * 4 + j;
        for (int n2 = 0; n2 < 4; n2++)
            pacc[(prow + qg) * 64 + n2 * 16 + lr] = acc[n2][j];
        if (lr == 0) { float2 v; v.x = m_run[j]; v.y = l_run[j]; pml[prow + qg] = v; }
    }
}

// ---------------- combine NSPLIT partials -> attnb bf16 [b][q][768] ----------------
__global__ __launch_bounds__(256) void attn_combine_kernel(
    const float* __restrict__ pacc, const float2* __restrict__ pml,
    unsigned short* __restrict__ attnb)
{
    const int idx = (blockIdx.x * 256 + threadIdx.x) * 4;  // grid covers BHS*64
    const int r = idx >> 6, d = idx & 63;
    float2 ml[NSPLIT];
    float mx = -3.0e38f;
    for (int s = 0; s < NSPLIT; s++) {
        ml[s] = pml[(size_t)s * BHS + r];
        mx = fmaxf(mx, ml[s].x);
    }
    float wgt[NSPLIT], L = 0.f;
    for (int s = 0; s < NSPLIT; s++) {
        wgt[s] = __expf(ml[s].x - mx);
        L += ml[s].y * wgt[s];
    }
    const float inv = (L > 0.f) ? 1.f / L : 0.f;
    float4 o = {0.f, 0.f, 0.f, 0.f};
    for (int s = 0; s < NSPLIT; s++) {
        const float4 a = *reinterpret_cast<const float4*>(&pacc[((size_t)s * BHS + r) * 64 + d]);
        o.x += a.x * wgt[s]; o.y += a.y * wgt[s];
        o.z += a.z * wgt[s]; o.w += a.w * wgt[s];
    }
    const int bh = r >> 10, q = r & 1023;
    const int b = bh / H_, h = bh - b * H_;
    ushort4 ov;
    ov.x = f2bf(o.x * inv); ov.y = f2bf(o.y * inv);
    ov.z = f2bf(o.z * inv); ov.w = f2bf(o.w * inv);
    *reinterpret_cast<ushort4*>(&attnb[((size_t)(b * S_ + q)) * D_ + h * HD_ + d]) = ov;
}

extern "C" void kernel_launch(void* const* d_in, const int* in_sizes, int n_in,
                              void* d_out, int out_size, void* d_ws, size_t ws_size,
                              hipStream_t stream)
{
    const float* x    = (const float*)d_in[0];
    const void*  adj  = d_in[1];
    const float* ea   = (const float*)d_in[2];
    const int*   ei   = (const int*)d_in[3];
    const float* g1   = (const float*)d_in[4];
    const float* bn1  = (const float*)d_in[5];
    const float* Wq   = (const float*)d_in[6];
    const float* bq   = (const float*)d_in[7];
    const float* Wk   = (const float*)d_in[8];
    const float* bk   = (const float*)d_in[9];
    const float* Wv   = (const float*)d_in[10];
    const float* bv   = (const float*)d_in[11];
    const float* Wo   = (const float*)d_in[12];
    const float* bo   = (const float*)d_in[13];
    const float* g2   = (const float*)d_in[14];
    const float* bn2  = (const float*)d_in[15];
    const float* W1   = (const float*)d_in[16];
    const float* mb1  = (const float*)d_in[17];
    const float* W2   = (const float*)d_in[18];
    const float* mb2  = (const float*)d_in[19];
    const float* epW1 = (const float*)d_in[20];
    const float* epb1 = (const float*)d_in[21];
    const float* epW2 = (const float*)d_in[22];
    const float* epb2 = (const float*)d_in[23];

    char* ws = (char*)d_ws;
    size_t off = 0;
    auto carve = [&](size_t bytes) -> void* {
        void* p = ws + off;
        off += (bytes + 255) & ~(size_t)255;
        return p;
    };
    unsigned short* wqkvt = (unsigned short*)carve((size_t)QS_ * D_ * 2);
    unsigned short* wot   = (unsigned short*)carve((size_t)D_ * D_ * 2);
    unsigned short* w1t   = (unsigned short*)carve((size_t)FF_ * D_ * 2);
    unsigned short* w2t   = (unsigned short*)carve((size_t)D_ * FF_ * 2);
    float*          bqkv  = (float*)carve((size_t)QS_ * 4);
    float*          proj  = (float*)carve((size_t)E_ * H_ * 4);
    int*            winner= (int*)carve((size_t)S_ * S_ * 4);
    unsigned short* ebias = (unsigned short*)carve((size_t)H_ * S_ * S_ * 2);  // 25.2 MB, reused as W2 partials
    unsigned int*   mpk   = (unsigned int*)carve((size_t)B_ * S_ * 32 * 4);
    unsigned short* nxb   = (unsigned short*)carve((size_t)B_ * S_ * D_ * 2);  // reused as ln2b
    unsigned short* attnb = (unsigned short*)carve((size_t)B_ * S_ * D_ * 2);
    unsigned short* qkv   = (unsigned short*)carve((size_t)B_ * S_ * QS_ * 2);
    unsigned short* vtb   = (unsigned short*)carve((size_t)B_ * S_ * D_ * 2);
    float*          x2f   = (float*)carve((size_t)B_ * S_ * D_ * 4);
    float*          pacc  = (float*)carve((size_t)NSPLIT * BHS * 64 * 4);
    float2*         pml   = (float2*)carve((size_t)NSPLIT * BHS * 8);
    unsigned short* ln2b = nxb;
    unsigned short* hb   = qkv;           // [2048][3072] bf16 aliases qkv+vtb (dead after attn)
    float*          pw2  = (float*)ebias; // W2 split-K partials (4x6.29MB) alias ebias (dead after attn)

    const int M = B_ * S_;  // 2048

    // mask pack + winner fill (adj only)
    maskpack_kernel<<<dim3(S_, B_), 256, 0, stream>>>(adj, mpk, winner);

    // all weight transposes + bias concat (1 launch)
    wtrans_all_kernel<<<dim3(96, 24, 6), 256, 0, stream>>>(
        Wq, Wk, Wv, Wo, W1, W2, wqkvt, wot, w1t, w2t, bq, bk, bv, bqkv);

    // LN1
    ln_kernel<<<M, 256, 0, stream>>>(x, g1, bn1, nxb);

    // fused QKV (bf16 out, Q cols scaled by 0.125)
    gemm128_kernel<false, true, false><<<dim3(QS_ / 128, M / 128), 256, 0, stream>>>(
        nxb, wqkvt, bqkv, qkv, M, QS_, D_, D_, 768);

    // V transpose
    vtrans_kernel<<<dim3(S_ / 64, H_, B_), 256, 0, stream>>>(qkv, vtb);

    // edge bias pipeline
    edge_proj_scatter_kernel<<<(E_ * H_) / 256, 256, 0, stream>>>(
        ea, epW1, epb1, epW2, epb2, ei, proj, winner);
    ebias_kernel<<<S_, 256, 0, stream>>>(winner, proj, ebias);

    // attention (KV-split x2) + combine
    attn_mfma_kernel<<<dim3(16 * NSPLIT, H_, B_), 256, 0, stream>>>(
        qkv, vtb, ebias, mpk, pacc, pml);
    attn_combine_kernel<<<(BHS * 64) / 1024, 256, 0, stream>>>(pacc, pml, attnb);

    // Wo + residual(x) -> x2 (f32)
    gemm_kernel<true, false><<<dim3(D_ / 64, M / 64), 256, 0, stream>>>(
        attnb, wot, bo, x, x2f, M, D_, D_);

    // LN2
    ln_kernel<<<M, 256, 0, stream>>>(x2f, g2, bn2, ln2b);

    // MLP
    gemm128_kernel<true, true, false><<<dim3(FF_ / 128, M / 128), 256, 0, stream>>>(
        ln2b, w1t, mb1, hb, M, FF_, D_, D_, 0);
    gemm128_kernel<false, false, true><<<dim3(D_ / 128, M / 128, NSPLIT_W2), 256, 0, stream>>>(
        hb, w2t, mb2, pw2, M, D_, FF_, FF_ / NSPLIT_W2, 0);
    w2_reduce_kernel<<<(M * D_) / 1024, 256, 0, stream>>>(pw2, x2f, mb2, (float*)d_out);
}

// Round 7
// 182.268 us; speedup vs baseline: 1.1380x; 1.0486x over previous
//
#include <hip/hip_runtime.h>
#include <hip/hip_bf16.h>

#define B_ 2
#define S_ 1024
#define D_ 768
#define H_ 12
#define HD_ 64
#define FF_ 3072
#define E_ 32768
#define QS_ 2304   // fused QKV row stride
#define NSPLIT 4   // attention KV splits (bf16 partials)
#define NSPLIT_W2 4
#define BHS (B_ * H_ * S_)   // 24576 partial rows per split

typedef short bf16x8 __attribute__((ext_vector_type(8)));
typedef float f32x4 __attribute__((ext_vector_type(4)));

// XOR swizzle: 8-elem seg s of row r lives at elem offset SW(r,s)
#define SW(row, seg) ((((seg) ^ ((row) & 7)) * 8))

__device__ __forceinline__ unsigned short f2bf(float f) {
    __hip_bfloat16 h = __float2bfloat16(f);
    return __builtin_bit_cast(unsigned short, h);
}
__device__ __forceinline__ float bf2f(unsigned short u) {
    unsigned int v = ((unsigned int)u) << 16;
    return __builtin_bit_cast(float, v);
}
__device__ __forceinline__ float gelu_exact(float x) {
    return 0.5f * x * (1.0f + erff(x * 0.70710678118654752f));
}
// async global->LDS, 16B per lane; LDS dest is wave-uniform base + lane*16
__device__ __forceinline__ void gload_lds16(const unsigned short* g, unsigned short* l) {
    __builtin_amdgcn_global_load_lds((const __attribute__((address_space(1))) void*)g,
                                     (__attribute__((address_space(3))) void*)l, 16, 0, 0);
}

// ================= fused prologue: maskpack+winnerfill | wtrans x6 | LN1 =================
// flat grid: [0,2048) maskpack, [2048,8960) wtrans, [8960,11008) LN1
__global__ __launch_bounds__(256) void prep_kernel(
    const void* __restrict__ adj, unsigned int* __restrict__ mp, int* __restrict__ winner,
    const float* __restrict__ Wq, const float* __restrict__ Wk, const float* __restrict__ Wv,
    const float* __restrict__ Wo, const float* __restrict__ W1, const float* __restrict__ W2,
    unsigned short* __restrict__ wqkvt, unsigned short* __restrict__ wot,
    unsigned short* __restrict__ w1t, unsigned short* __restrict__ w2t,
    const float* __restrict__ bq, const float* __restrict__ bk, const float* __restrict__ bv,
    float* __restrict__ bqkv,
    const float* __restrict__ x, const float* __restrict__ g1, const float* __restrict__ bn1,
    unsigned short* __restrict__ nxb)
{
    __shared__ float tile[32][33];
    __shared__ unsigned int words[32];
    __shared__ int u8f;
    __shared__ float red[8];
    const int blk = blockIdx.x;
    const int t = threadIdx.x;

    if (blk < 2048) {
        // ---- mask bit-pack (+winner -1 fill on b==0) ----
        const int b = blk >> 10, q = blk & 1023;
        if (b == 0) {
            int4 v; v.x = -1; v.y = -1; v.z = -1; v.w = -1;
            reinterpret_cast<int4*>(winner)[q * 256 + t] = v;
        }
        if (t < 32) words[t] = 0;
        if (t == 0) u8f = 0;
        __syncthreads();
        const unsigned int* row8 = (const unsigned int*)((const unsigned char*)adj + ((size_t)b * S_ + q) * S_);
        const unsigned int* row32 = (const unsigned int*)((const int*)adj + ((size_t)b * S_ + q) * S_);
        const unsigned int v = row8[t];
        if (v & 0xFF00FF00u) atomicOr(&u8f, 1);
        __syncthreads();
        if (u8f) {
            unsigned int nib = 0;
            if (v & 0x000000FFu) nib |= 1u;
            if (v & 0x0000FF00u) nib |= 2u;
            if (v & 0x00FF0000u) nib |= 4u;
            if (v & 0xFF000000u) nib |= 8u;
            if (nib) atomicOr(&words[t >> 3], nib << ((t & 7) * 4));
        } else {
            for (int i = 0; i < 4; i++) {
                const int k = i * 256 + t;
                if (row32[k]) atomicOr(&words[k >> 5], 1u << (k & 31));
            }
        }
        __syncthreads();
        if (t < 32) mp[((size_t)b * S_ + q) * 32 + t] = words[t];
    } else if (blk < 8960) {
        // ---- weight transposes + bias concat ----
        const int w = blk - 2048;
        const float* src; unsigned short* dst; int K, N, nb, kb;
        if (w < 2304) {
            const int z = w / 576, r = w - z * 576;
            K = 768; N = 768; kb = (r / 24) * 32; nb = (r % 24) * 32;
            src = (z == 0) ? Wq : (z == 1) ? Wk : (z == 2) ? Wv : Wo;
            dst = (z == 3) ? wot : wqkvt + (size_t)z * 768 * 768;
        } else if (w < 4608) {
            const int r = w - 2304;
            K = 768; N = 3072; nb = (r % 96) * 32; kb = (r / 96) * 32;
            src = W1; dst = w1t;
        } else {
            const int r = w - 4608;
            K = 3072; N = 768; kb = (r % 96) * 32; nb = (r / 96) * 32;
            src = W2; dst = w2t;
        }
        const int tx = t & 31, ty = t >> 5;
        for (int r = 0; r < 32; r += 8)
            tile[ty + r][tx] = src[(size_t)(kb + ty + r) * N + nb + tx];
        __syncthreads();
        for (int r = 0; r < 32; r += 8)
            dst[(size_t)(nb + ty + r) * K + kb + tx] = f2bf(tile[tx][ty + r]);
        if (w == 0) {
            for (int i = t; i < QS_; i += 256)
                bqkv[i] = (i < 768) ? bq[i] : (i < 1536) ? bk[i - 768] : bv[i - 1536];
        }
    } else {
        // ---- LayerNorm1 ----
        const int row = blk - 8960;
        const float* xr = x + (size_t)row * D_;
        float v0 = xr[t], v1 = xr[t + 256], v2 = xr[t + 512];
        float s = v0 + v1 + v2, s2 = v0 * v0 + v1 * v1 + v2 * v2;
        for (int m = 32; m; m >>= 1) { s += __shfl_xor(s, m); s2 += __shfl_xor(s2, m); }
        const int w = t >> 6;
        if ((t & 63) == 0) { red[w] = s; red[4 + w] = s2; }
        __syncthreads();
        s = red[0] + red[1] + red[2] + red[3];
        s2 = red[4] + red[5] + red[6] + red[7];
        const float mean = s * (1.f / D_);
        const float var = s2 * (1.f / D_) - mean * mean;
        const float rstd = rsqrtf(var + 1e-5f);
        unsigned short* orow = nxb + (size_t)row * D_;
        orow[t]       = f2bf((v0 - mean) * rstd * g1[t]       + bn1[t]);
        orow[t + 256] = f2bf((v1 - mean) * rstd * g1[t + 256] + bn1[t + 256]);
        orow[t + 512] = f2bf((v2 - mean) * rstd * g1[t + 512] + bn1[t + 512]);
    }
}

// ---------------- LayerNorm (standalone, for LN2) ----------------
__global__ __launch_bounds__(256) void ln_kernel(
    const float* __restrict__ x, const float* __restrict__ g,
    const float* __restrict__ b, unsigned short* __restrict__ out)
{
    const int row = blockIdx.x;
    const int t = threadIdx.x;
    const float* xr = x + (size_t)row * D_;
    float v0 = xr[t], v1 = xr[t + 256], v2 = xr[t + 512];
    float s = v0 + v1 + v2, s2 = v0 * v0 + v1 * v1 + v2 * v2;
    for (int m = 32; m; m >>= 1) { s += __shfl_xor(s, m); s2 += __shfl_xor(s2, m); }
    __shared__ float red[8];
    const int w = t >> 6;
    if ((t & 63) == 0) { red[w] = s; red[4 + w] = s2; }
    __syncthreads();
    s = red[0] + red[1] + red[2] + red[3];
    s2 = red[4] + red[5] + red[6] + red[7];
    const float mean = s * (1.f / D_);
    const float var = s2 * (1.f / D_) - mean * mean;
    const float rstd = rsqrtf(var + 1e-5f);
    unsigned short* orow = out + (size_t)row * D_;
    orow[t]       = f2bf((v0 - mean) * rstd * g[t]       + b[t]);
    orow[t + 256] = f2bf((v1 - mean) * rstd * g[t + 256] + b[t + 256]);
    orow[t + 512] = f2bf((v2 - mean) * rstd * g[t + 512] + b[t + 512]);
}

// ---------------- edge MLP + scatter (after prep: winner init complete) ----------------
__global__ __launch_bounds__(256) void edge_proj_scatter_kernel(
    const float* __restrict__ ea, const float* __restrict__ W1, const float* __restrict__ b1,
    const float* __restrict__ W2, const float* __restrict__ b2,
    const int* __restrict__ ei, float* __restrict__ proj, int* __restrict__ winner)
{
    const int tid = blockIdx.x * 256 + threadIdx.x;
    const int e = tid / H_, h = tid - e * H_;
    const float a = ea[e];
    float s = 0.f;
    for (int j = 0; j < 16; j++) {
        const float tv = a * W1[h * 16 + j] + b1[h * 16 + j];
        s += gelu_exact(tv) * W2[h * 16 + j];
    }
    proj[tid] = s + b2[h];
    if (h == 0) {
        const int sn = ei[e], dn = ei[E_ + e];
        atomicMax(&winner[sn * S_ + dn], e);
    }
}

// ================= fused mid: vtrans | ebias =================
// flat grid: [0,384) vtrans, [384,1408) ebias
__global__ __launch_bounds__(256) void mid_kernel(
    const unsigned short* __restrict__ qkv, unsigned short* __restrict__ vt,
    const int* __restrict__ winner, const float* __restrict__ proj,
    unsigned short* __restrict__ ebias)
{
    __shared__ unsigned short T[64][68];
    const int blk = blockIdx.x;
    const int t = threadIdx.x;
    if (blk < 384) {
        // ---- V transpose: qkv V cols -> vt[b][h][d][s] ----
        const int s0 = (blk & 15) * 64;
        const int rest = blk >> 4;
        const int h = rest % 12, b = rest / 12;
        const int r = t >> 2, seg = t & 3;
        const unsigned short* src = qkv + (size_t)(b * S_ + s0 + r) * QS_ + 1536 + h * HD_ + seg * 16;
        *reinterpret_cast<uint4*>(&T[r][seg * 16])     = *reinterpret_cast<const uint4*>(src);
        *reinterpret_cast<uint4*>(&T[r][seg * 16 + 8]) = *reinterpret_cast<const uint4*>(src + 8);
        __syncthreads();
        unsigned short tmp[16];
        for (int i = 0; i < 16; i++) tmp[i] = T[seg * 16 + i][r];
        unsigned short* dst = vt + ((size_t)(b * H_ + h) * HD_ + r) * S_ + s0 + seg * 16;
        *reinterpret_cast<uint4*>(dst)     = *reinterpret_cast<uint4*>(&tmp[0]);
        *reinterpret_cast<uint4*>(dst + 8) = *reinterpret_cast<uint4*>(&tmp[8]);
    } else {
        // ---- ebias[h][q][k] bf16 ----
        const int q = blk - 384;
        const int k4 = t * 4;
        const int4 wv = *reinterpret_cast<const int4*>(&winner[q * S_ + k4]);
        for (int h = 0; h < H_; h++) {
            unsigned int lo = 0, hi = 0;
            if (wv.x >= 0) lo |= (unsigned int)f2bf(proj[(size_t)wv.x * H_ + h]);
            if (wv.y >= 0) lo |= ((unsigned int)f2bf(proj[(size_t)wv.y * H_ + h])) << 16;
            if (wv.z >= 0) hi |= (unsigned int)f2bf(proj[(size_t)wv.z * H_ + h]);
            if (wv.w >= 0) hi |= ((unsigned int)f2bf(proj[(size_t)wv.w * H_ + h])) << 16;
            uint2 val; val.x = lo; val.y = hi;
            *reinterpret_cast<uint2*>(&ebias[((size_t)h * S_ + q) * S_ + k4]) = val;
        }
    }
}

// ---------------- 64x64 GEMM (Wo): C = (A @ Bt^T + bias) [+res] ----------------
template<bool RES, bool OUTBF>
__global__ __launch_bounds__(256) void gemm_kernel(
    const unsigned short* __restrict__ A, const unsigned short* __restrict__ Bt,
    const float* __restrict__ bias, const float* __restrict__ res,
    void* __restrict__ outp, int M, int N, int K)
{
    __shared__ unsigned short As[64][40];
    __shared__ unsigned short Bs[64][40];
    const int m0 = blockIdx.y * 64, n0 = blockIdx.x * 64;
    const int t = threadIdx.x;
    const int w = t >> 6, l = t & 63;
    const int wm = w >> 1, wn = w & 1;
    const int r = l & 15, g = l >> 4;
    const int srow = t >> 2, sseg = t & 3;
    f32x4 acc[2][2] = {};
    for (int k0 = 0; k0 < K; k0 += 32) {
        __syncthreads();
        const uint4 av = *reinterpret_cast<const uint4*>(A + (size_t)(m0 + srow) * K + k0 + sseg * 8);
        *reinterpret_cast<uint4*>(&As[srow][sseg * 8]) = av;
        const uint4 bv = *reinterpret_cast<const uint4*>(Bt + (size_t)(n0 + srow) * K + k0 + sseg * 8);
        *reinterpret_cast<uint4*>(&Bs[srow][sseg * 8]) = bv;
        __syncthreads();
        bf16x8 af[2], bfr[2];
        af[0]  = *reinterpret_cast<const bf16x8*>(&As[wm * 32 + r][g * 8]);
        af[1]  = *reinterpret_cast<const bf16x8*>(&As[wm * 32 + 16 + r][g * 8]);
        bfr[0] = *reinterpret_cast<const bf16x8*>(&Bs[wn * 32 + r][g * 8]);
        bfr[1] = *reinterpret_cast<const bf16x8*>(&Bs[wn * 32 + 16 + r][g * 8]);
        for (int m = 0; m < 2; m++)
            for (int n = 0; n < 2; n++)
                acc[m][n] = __builtin_amdgcn_mfma_f32_16x16x32_bf16(af[m], bfr[n], acc[m][n], 0, 0, 0);
    }
    for (int m = 0; m < 2; m++)
        for (int n = 0; n < 2; n++) {
            const int col = n0 + wn * 32 + n * 16 + r;
            const float bvv = bias[col];
            for (int j = 0; j < 4; j++) {
                const int row = m0 + wm * 32 + m * 16 + g * 4 + j;
                float v = acc[m][n][j] + bvv;
                if (RES) v += res[(size_t)row * N + col];
                if (OUTBF) ((unsigned short*)outp)[(size_t)row * N + col] = f2bf(v);
                else       ((float*)outp)[(size_t)row * N + col] = v;
            }
        }
}

// ---------------- 128x128 GEMM, BK=64, global_load_lds + pre-swizzled source ----------------
// SPLITK: partial out [z][M][N] (bf16 if OUTBF else f32); else epilogue (bias, 0.125 cols, GELU)
template<bool GELU, bool OUTBF, bool SPLITK>
__global__ __launch_bounds__(256) void gemm128_kernel(
    const unsigned short* __restrict__ A, const unsigned short* __restrict__ Bt,
    const float* __restrict__ bias, void* __restrict__ outp,
    int M, int N, int K, int klen, int scale_below)
{
    __shared__ unsigned short As[128][64];
    __shared__ unsigned short Bs[128][64];
    const int m0 = blockIdx.y * 128, n0 = blockIdx.x * 128;
    const int t = threadIdx.x;
    const int w = t >> 6, l = t & 63;
    const int wm = w >> 1, wn = w & 1;
    const int lr = l & 15, g = l >> 4;
    const int lrow8 = l >> 3;            // row within 8-row chunk
    const int lseg = (l & 7) ^ lrow8;    // pre-swizzled global source seg
    const int kbeg = SPLITK ? blockIdx.z * klen : 0;
    const int kend = SPLITK ? kbeg + klen : K;
    f32x4 acc[4][4] = {};
    for (int k0 = kbeg; k0 < kend; k0 += 64) {
        __syncthreads();
        for (int j = 0; j < 4; j++) {
            const int q = w * 4 + j;           // chunk 0..15 (8 rows each)
            const int row = q * 8 + lrow8;
            gload_lds16(A  + (size_t)(m0 + row) * K + k0 + lseg * 8, &As[q * 8][0]);
            gload_lds16(Bt + (size_t)(n0 + row) * K + k0 + lseg * 8, &Bs[q * 8][0]);
        }
        __syncthreads();
        for (int kk = 0; kk < 2; kk++) {
            bf16x8 af[4], bfr[4];
            for (int m = 0; m < 4; m++) {
                const int r = wm * 64 + m * 16 + lr;
                af[m] = *reinterpret_cast<const bf16x8*>(&As[r][SW(r, kk * 4 + g)]);
            }
            for (int n = 0; n < 4; n++) {
                const int r = wn * 64 + n * 16 + lr;
                bfr[n] = *reinterpret_cast<const bf16x8*>(&Bs[r][SW(r, kk * 4 + g)]);
            }
            for (int m = 0; m < 4; m++)
                for (int n = 0; n < 4; n++)
                    acc[m][n] = __builtin_amdgcn_mfma_f32_16x16x32_bf16(af[m], bfr[n], acc[m][n], 0, 0, 0);
        }
    }
    if (SPLITK) {
        for (int m = 0; m < 4; m++)
            for (int n = 0; n < 4; n++) {
                const int col = n0 + wn * 64 + n * 16 + lr;
                for (int j = 0; j < 4; j++) {
                    const int row = m0 + wm * 64 + m * 16 + g * 4 + j;
                    if (OUTBF) ((unsigned short*)outp)[((size_t)blockIdx.z * M + row) * N + col] = f2bf(acc[m][n][j]);
                    else       ((float*)outp)[((size_t)blockIdx.z * M + row) * N + col] = acc[m][n][j];
                }
            }
    } else {
        for (int m = 0; m < 4; m++)
            for (int n = 0; n < 4; n++) {
                const int col = n0 + wn * 64 + n * 16 + lr;
                const float scl = (col < scale_below) ? 0.125f : 1.0f;
                const float bvv = bias[col];
                for (int j = 0; j < 4; j++) {
                    const int row = m0 + wm * 64 + m * 16 + g * 4 + j;
                    float v = (acc[m][n][j] + bvv) * scl;
                    if (GELU) v = gelu_exact(v);
                    if (OUTBF) ((unsigned short*)outp)[(size_t)row * N + col] = f2bf(v);
                    else       ((float*)outp)[(size_t)row * N + col] = v;
                }
            }
    }
}

// ---------------- W2 reduce: d_out = x2 + b2 + sum_z bf16 part[z] ----------------
__global__ __launch_bounds__(256) void w2_reduce_kernel(
    const unsigned short* __restrict__ part, const float* __restrict__ x2,
    const float* __restrict__ b2, float* __restrict__ out)
{
    const int idx = (blockIdx.x * 256 + threadIdx.x) * 4;
    const int col = idx % D_;
    const float4 xr = *reinterpret_cast<const float4*>(&x2[idx]);
    const float4 bb = *reinterpret_cast<const float4*>(&b2[col]);
    float4 o;
    o.x = xr.x + bb.x; o.y = xr.y + bb.y; o.z = xr.z + bb.z; o.w = xr.w + bb.w;
    for (int s = 0; s < NSPLIT_W2; s++) {
        const uint2 p = *reinterpret_cast<const uint2*>(&part[(size_t)s * B_ * S_ * D_ + idx]);
        o.x += bf2f((unsigned short)(p.x & 0xFFFF));
        o.y += bf2f((unsigned short)(p.x >> 16));
        o.z += bf2f((unsigned short)(p.y & 0xFFFF));
        o.w += bf2f((unsigned short)(p.y >> 16));
    }
    *reinterpret_cast<float4*>(&out[idx]) = o;
}

// ---------------- MFMA flash attention, KV-split: block = (qt, sp, h, b) ----------------
__global__ __launch_bounds__(256) void attn_mfma_kernel(
    const unsigned short* __restrict__ qkv,   // Q col 0, K col 768, stride QS_
    const unsigned short* __restrict__ vt,    // [b][h][d][s]
    const unsigned short* __restrict__ ebias, // [h][q][k]
    const unsigned int* __restrict__ mp,      // [b][q][32]
    unsigned short* __restrict__ pacc,        // [sp][bh][q][64] bf16
    float2* __restrict__ pml)                 // [sp][bh][q]
{
    __shared__ unsigned short Ks[64][64];
    __shared__ unsigned short Vs[64][64];
    __shared__ unsigned short Eb[64][72];
    __shared__ unsigned int   Mw[64][2];
    __shared__ unsigned short Ps[4][16][64];
    const int t = threadIdx.x;
    const int w = t >> 6, l = t & 63;
    const int lr = l & 15, g = l >> 4;
    const int qt = blockIdx.x & 15, sp = blockIdx.x >> 4;
    const int q0 = qt * 64;
    const int h = blockIdx.y, b = blockIdx.z;
    const int bh = b * H_ + h;
    const size_t qbase = (size_t)b * S_ * QS_ + h * HD_;
    const size_t kbase = qbase + 768;
    const size_t vtbase = (size_t)bh * HD_ * S_;

    const int qrow = q0 + w * 16 + lr;
    const bf16x8 af0 = *reinterpret_cast<const bf16x8*>(qkv + qbase + (size_t)qrow * QS_ + g * 8);
    const bf16x8 af1 = *reinterpret_cast<const bf16x8*>(qkv + qbase + (size_t)qrow * QS_ + 32 + g * 8);

    float m_run[4], l_run[4];
    f32x4 acc[4] = {};
    for (int j = 0; j < 4; j++) { m_run[j] = -3.0e38f; l_run[j] = 0.f; }

    const int srow = t >> 2, sseg = t & 3;
    const int kt_beg = sp * (S_ / NSPLIT), kt_end = kt_beg + S_ / NSPLIT;
    for (int kt = kt_beg; kt < kt_end; kt += 64) {
        __syncthreads();
        {
            const unsigned short* ksrc = qkv + kbase + (size_t)(kt + srow) * QS_ + sseg * 16;
            *reinterpret_cast<uint4*>(&Ks[srow][SW(srow, sseg * 2)])     = *reinterpret_cast<const uint4*>(ksrc);
            *reinterpret_cast<uint4*>(&Ks[srow][SW(srow, sseg * 2 + 1)]) = *reinterpret_cast<const uint4*>(ksrc + 8);
            const unsigned short* vsrc = vt + vtbase + (size_t)srow * S_ + kt + sseg * 16;
            *reinterpret_cast<uint4*>(&Vs[srow][SW(srow, sseg * 2)])     = *reinterpret_cast<const uint4*>(vsrc);
            *reinterpret_cast<uint4*>(&Vs[srow][SW(srow, sseg * 2 + 1)]) = *reinterpret_cast<const uint4*>(vsrc + 8);
            const unsigned short* esrc = ebias + ((size_t)h * S_ + q0 + srow) * S_ + kt + sseg * 16;
            *reinterpret_cast<uint4*>(&Eb[srow][sseg * 16])     = *reinterpret_cast<const uint4*>(esrc);
            *reinterpret_cast<uint4*>(&Eb[srow][sseg * 16 + 8]) = *reinterpret_cast<const uint4*>(esrc + 8);
            if (t < 128) Mw[t >> 1][t & 1] = mp[((size_t)b * S_ + q0 + (t >> 1)) * 32 + (kt >> 5) + (t & 1)];
        }
        __syncthreads();
        f32x4 sc[4];
        for (int n = 0; n < 4; n++) {
            const int r = n * 16 + lr;
            const bf16x8 b0 = *reinterpret_cast<const bf16x8*>(&Ks[r][SW(r, g)]);
            const bf16x8 b1 = *reinterpret_cast<const bf16x8*>(&Ks[r][SW(r, 4 + g)]);
            f32x4 z = {};
            z = __builtin_amdgcn_mfma_f32_16x16x32_bf16(af0, b0, z, 0, 0, 0);
            z = __builtin_amdgcn_mfma_f32_16x16x32_bf16(af1, b1, z, 0, 0, 0);
            sc[n] = z;
        }
        float tmax[4] = {-3.0e38f, -3.0e38f, -3.0e38f, -3.0e38f};
        for (int n = 0; n < 4; n++) {
            for (int j = 0; j < 4; j++) {
                const int rq = w * 16 + g * 4 + j;
                const unsigned int word = Mw[rq][n >> 1];
                const bool msk = (word >> ((n & 1) * 16 + lr)) & 1;
                float sval;
                if (msk) sval = sc[n][j] + bf2f(Eb[rq][n * 16 + lr]);
                else sval = -1e9f;
                sc[n][j] = sval;
                tmax[j] = fmaxf(tmax[j], sval);
            }
        }
        float pscale[4];
        for (int j = 0; j < 4; j++) {
            float tm = tmax[j];
            tm = fmaxf(tm, __shfl_xor(tm, 1));
            tm = fmaxf(tm, __shfl_xor(tm, 2));
            tm = fmaxf(tm, __shfl_xor(tm, 4));
            tm = fmaxf(tm, __shfl_xor(tm, 8));
            const float mnew = fmaxf(m_run[j], tm);
            pscale[j] = __expf(m_run[j] - mnew);
            m_run[j] = mnew;
            l_run[j] *= pscale[j];
        }
        float psum[4] = {0.f, 0.f, 0.f, 0.f};
        for (int n = 0; n < 4; n++) {
            for (int j = 0; j < 4; j++) {
                const float p = __expf(sc[n][j] - m_run[j]);
                psum[j] += p;
                const int row = g * 4 + j;
                Ps[w][row][SW(row, n * 2 + (lr >> 3)) + (lr & 7)] = f2bf(p);
            }
        }
        for (int j = 0; j < 4; j++) {
            float s = psum[j];
            s += __shfl_xor(s, 1); s += __shfl_xor(s, 2);
            s += __shfl_xor(s, 4); s += __shfl_xor(s, 8);
            l_run[j] += s;
            for (int n2 = 0; n2 < 4; n2++) acc[n2][j] *= pscale[j];
        }
        const bf16x8 pa0 = *reinterpret_cast<const bf16x8*>(&Ps[w][lr][SW(lr, g)]);
        const bf16x8 pa1 = *reinterpret_cast<const bf16x8*>(&Ps[w][lr][SW(lr, 4 + g)]);
        for (int n2 = 0; n2 < 4; n2++) {
            const int r = n2 * 16 + lr;
            const bf16x8 vb0 = *reinterpret_cast<const bf16x8*>(&Vs[r][SW(r, g)]);
            const bf16x8 vb1 = *reinterpret_cast<const bf16x8*>(&Vs[r][SW(r, 4 + g)]);
            acc[n2] = __builtin_amdgcn_mfma_f32_16x16x32_bf16(pa0, vb0, acc[n2], 0, 0, 0);
            acc[n2] = __builtin_amdgcn_mfma_f32_16x16x32_bf16(pa1, vb1, acc[n2], 0, 0, 0);
        }
    }
    // ---- partial epilogue (bf16) ----
    const size_t prow = (size_t)sp * BHS + (size_t)bh * S_;
    for (int j = 0; j < 4; j++) {
        const int qg = q0 + w * 16 + g * 4 + j;
        for (int n2 = 0; n2 < 4; n2++)
            pacc[(prow + qg) * 64 + n2 * 16 + lr] = f2bf(acc[n2][j]);
        if (lr == 0) { float2 v; v.x = m_run[j]; v.y = l_run[j]; pml[prow + qg] = v; }
    }
}

// ---------------- combine NSPLIT bf16 partials -> attnb bf16 [b][q][768] ----------------
__global__ __launch_bounds__(256) void attn_combine_kernel(
    const unsigned short* __restrict__ pacc, const float2* __restrict__ pml,
    unsigned short* __restrict__ attnb)
{
    const int idx = (blockIdx.x * 256 + threadIdx.x) * 4;  // grid covers BHS*64
    const int r = idx >> 6, d = idx & 63;
    float2 ml[NSPLIT];
    float mx = -3.0e38f;
    for (int s = 0; s < NSPLIT; s++) {
        ml[s] = pml[(size_t)s * BHS + r];
        mx = fmaxf(mx, ml[s].x);
    }
    float wgt[NSPLIT], L = 0.f;
    for (int s = 0; s < NSPLIT; s++) {
        wgt[s] = __expf(ml[s].x - mx);
        L += ml[s].y * wgt[s];
    }
    const float inv = (L > 0.f) ? 1.f / L : 0.f;
    float4 o = {0.f, 0.f, 0.f, 0.f};
    for (int s = 0; s < NSPLIT; s++) {
        const uint2 p = *reinterpret_cast<const uint2*>(&pacc[((size_t)s * BHS + r) * 64 + d]);
        o.x += bf2f((unsigned short)(p.x & 0xFFFF)) * wgt[s];
        o.y += bf2f((unsigned short)(p.x >> 16)) * wgt[s];
        o.z += bf2f((unsigned short)(p.y & 0xFFFF)) * wgt[s];
        o.w += bf2f((unsigned short)(p.y >> 16)) * wgt[s];
    }
    const int bh = r >> 10, q = r & 1023;
    const int b = bh / H_, h = bh - b * H_;
    ushort4 ov;
    ov.x = f2bf(o.x * inv); ov.y = f2bf(o.y * inv);
    ov.z = f2bf(o.z * inv); ov.w = f2bf(o.w * inv);
    *reinterpret_cast<ushort4*>(&attnb[((size_t)(b * S_ + q)) * D_ + h * HD_ + d]) = ov;
}

extern "C" void kernel_launch(void* const* d_in, const int* in_sizes, int n_in,
                              void* d_out, int out_size, void* d_ws, size_t ws_size,
                              hipStream_t stream)
{
    const float* x    = (const float*)d_in[0];
    const void*  adj  = d_in[1];
    const float* ea   = (const float*)d_in[2];
    const int*   ei   = (const int*)d_in[3];
    const float* g1   = (const float*)d_in[4];
    const float* bn1  = (const float*)d_in[5];
    const float* Wq   = (const float*)d_in[6];
    const float* bq   = (const float*)d_in[7];
    const float* Wk   = (const float*)d_in[8];
    const float* bk   = (const float*)d_in[9];
    const float* Wv   = (const float*)d_in[10];
    const float* bv   = (const float*)d_in[11];
    const float* Wo   = (const float*)d_in[12];
    const float* bo   = (const float*)d_in[13];
    const float* g2   = (const float*)d_in[14];
    const float* bn2  = (const float*)d_in[15];
    const float* W1   = (const float*)d_in[16];
    const float* mb1  = (const float*)d_in[17];
    const float* W2   = (const float*)d_in[18];
    const float* mb2  = (const float*)d_in[19];
    const float* epW1 = (const float*)d_in[20];
    const float* epb1 = (const float*)d_in[21];
    const float* epW2 = (const float*)d_in[22];
    const float* epb2 = (const float*)d_in[23];

    char* ws = (char*)d_ws;
    size_t off = 0;
    auto carve = [&](size_t bytes) -> void* {
        void* p = ws + off;
        off += (bytes + 255) & ~(size_t)255;
        return p;
    };
    unsigned short* wqkvt = (unsigned short*)carve((size_t)QS_ * D_ * 2);
    unsigned short* wot   = (unsigned short*)carve((size_t)D_ * D_ * 2);
    unsigned short* w1t   = (unsigned short*)carve((size_t)FF_ * D_ * 2);
    unsigned short* w2t   = (unsigned short*)carve((size_t)D_ * FF_ * 2);
    float*          bqkv  = (float*)carve((size_t)QS_ * 4);
    float*          proj  = (float*)carve((size_t)E_ * H_ * 4);
    int*            winner= (int*)carve((size_t)S_ * S_ * 4);
    unsigned short* ebias = (unsigned short*)carve((size_t)H_ * S_ * S_ * 2);  // 25.2 MB, reused as W2 partials
    unsigned int*   mpk   = (unsigned int*)carve((size_t)B_ * S_ * 32 * 4);
    unsigned short* nxb   = (unsigned short*)carve((size_t)B_ * S_ * D_ * 2);  // reused as ln2b
    unsigned short* attnb = (unsigned short*)carve((size_t)B_ * S_ * D_ * 2);
    unsigned short* qkv   = (unsigned short*)carve((size_t)B_ * S_ * QS_ * 2);
    unsigned short* vtb   = (unsigned short*)carve((size_t)B_ * S_ * D_ * 2);
    float*          x2f   = (float*)carve((size_t)B_ * S_ * D_ * 4);
    unsigned short* pacc  = (unsigned short*)carve((size_t)NSPLIT * BHS * 64 * 2);  // 12.6 MB bf16
    float2*         pml   = (float2*)carve((size_t)NSPLIT * BHS * 8);
    unsigned short* ln2b = nxb;
    unsigned short* hb   = qkv;                     // [2048][3072] bf16 aliases qkv+vtb (dead after attn)
    unsigned short* pw2  = (unsigned short*)ebias;  // W2 split-K bf16 partials alias ebias (dead after attn)

    const int M = B_ * S_;  // 2048

    // fused prologue: maskpack+winnerfill | wtrans x6 + bias concat | LN1
    prep_kernel<<<11008, 256, 0, stream>>>(
        adj, mpk, winner,
        Wq, Wk, Wv, Wo, W1, W2, wqkvt, wot, w1t, w2t, bq, bk, bv, bqkv,
        x, g1, bn1, nxb);

    // edge MLP + scatter (needs winner init from prep)
    edge_proj_scatter_kernel<<<(E_ * H_) / 256, 256, 0, stream>>>(
        ea, epW1, epb1, epW2, epb2, ei, proj, winner);

    // fused QKV (bf16 out, Q cols scaled by 0.125)
    gemm128_kernel<false, true, false><<<dim3(QS_ / 128, M / 128), 256, 0, stream>>>(
        nxb, wqkvt, bqkv, qkv, M, QS_, D_, D_, 768);

    // fused mid: vtrans | ebias
    mid_kernel<<<384 + S_, 256, 0, stream>>>(qkv, vtb, winner, proj, ebias);

    // attention (KV-split x4, bf16 partials) + combine
    attn_mfma_kernel<<<dim3(16 * NSPLIT, H_, B_), 256, 0, stream>>>(
        qkv, vtb, ebias, mpk, pacc, pml);
    attn_combine_kernel<<<(BHS * 64) / 1024, 256, 0, stream>>>(pacc, pml, attnb);

    // Wo + residual(x) -> x2 (f32)
    gemm_kernel<true, false><<<dim3(D_ / 64, M / 64), 256, 0, stream>>>(
        attnb, wot, bo, x, x2f, M, D_, D_);

    // LN2
    ln_kernel<<<M, 256, 0, stream>>>(x2f, g2, bn2, ln2b);

    // MLP
    gemm128_kernel<true, true, false><<<dim3(FF_ / 128, M / 128), 256, 0, stream>>>(
        ln2b, w1t, mb1, hb, M, FF_, D_, D_, 0);
    gemm128_kernel<false, true, true><<<dim3(D_ / 128, M / 128, NSPLIT_W2), 256, 0, stream>>>(
        hb, w2t, mb2, pw2, M, D_, FF_, FF_ / NSPLIT_W2, 0);
    w2_reduce_kernel<<<(M * D_) / 1024, 256, 0, stream>>>(pw2, x2f, mb2, (float*)d_out);
}